// Round 3
// baseline (5081.171 us; speedup 1.0000x reference)
//
#include <hip/hip_runtime.h>

// ---------------------------------------------------------------------------
// SLAYER SNN, correctness-first: all accumulation in f64 so our result is the
// true value to ~1e-13, far inside the reference's spike-decision margins
// (spikes are 0/1; one flipped decision = absmax 1.0, so we must land on the
// same side of theta as the reference on every one of ~1.5M decisions).
// ---------------------------------------------------------------------------

// z[b,o,t] = sum_f W[o,f] * x[b,f,t]   (x is binary spikes, W exact f32)
// Tile 32(o) x 64(t), K-tile 32, f64 accumulate.
__global__ __launch_bounds__(256) void gemm_kernel(
    const float* __restrict__ X,   // [B,F,T] (f32 0/1 spikes)
    const float* __restrict__ W,   // [O,F]   (f32)
    double* __restrict__ Z,        // [B,O,T] (f64)
    int O, int F, int T)
{
    const int KT = 32;
    int b  = blockIdx.z;
    int o0 = blockIdx.y * 32;
    int t0 = blockIdx.x * 64;

    __shared__ double Ws[32][33];   // +1 pad
    __shared__ double Xs[32][65];   // +1 pad

    int tid = threadIdx.x;
    int ty  = tid >> 4;            // 0..15 (o-direction)
    int tx  = tid & 15;            // 0..15 (t-direction)

    double acc[2][4] = {{0,0,0,0},{0,0,0,0}};
    const float* Xb = X + (size_t)b * F * T;

    for (int f0 = 0; f0 < F; f0 += KT) {
        #pragma unroll
        for (int i = 0; i < 4; ++i) {
            int idx = i * 256 + tid;
            int r = idx >> 5, c = idx & 31;
            int o = o0 + r, f = f0 + c;
            Ws[r][c] = (o < O && f < F) ? (double)W[(size_t)o * F + f] : 0.0;
        }
        #pragma unroll
        for (int i = 0; i < 8; ++i) {
            int idx = i * 256 + tid;
            int r = idx >> 6, c = idx & 63;
            int f = f0 + r, t = t0 + c;
            Xs[r][c] = (f < F && t < T) ? (double)Xb[(size_t)f * T + t] : 0.0;
        }
        __syncthreads();

        #pragma unroll
        for (int kk = 0; kk < KT; ++kk) {
            double xv[4];
            #pragma unroll
            for (int j = 0; j < 4; ++j) xv[j] = Xs[kk][tx * 4 + j];
            #pragma unroll
            for (int i = 0; i < 2; ++i) {
                double wv = Ws[ty * 2 + i][kk];
                #pragma unroll
                for (int j = 0; j < 4; ++j)
                    acc[i][j] = fma(wv, xv[j], acc[i][j]);
            }
        }
        __syncthreads();
    }

    double* Zb = Z + (size_t)b * O * T;
    #pragma unroll
    for (int i = 0; i < 2; ++i) {
        int o = o0 + ty * 2 + i;
        if (o >= O) continue;
        #pragma unroll
        for (int j = 0; j < 4; ++j) {
            int t = t0 + tx * 4 + j;
            if (t < T) Zb[(size_t)o * T + t] = acc[i][j];
        }
    }
}

// u[row,t] = sum_{k=0..min(t,99)} eps[k] * z[row,t-k], f64 table + f64 accum
__global__ __launch_bounds__(320) void psp_kernel(
    const double* __restrict__ Z, double* __restrict__ U, int T)
{
    __shared__ double zs[304];
    __shared__ double eps[100];
    int row = blockIdx.x;
    int tid = threadIdx.x;

    if (tid < 100) {
        double td = (double)tid;
        eps[tid] = (td / 10.0) * exp(1.0 - td / 10.0);
    }
    const double* z = Z + (size_t)row * T;
    if (tid < T) zs[tid] = z[tid];
    __syncthreads();

    if (tid < T) {
        int kmax = tid < 99 ? tid : 99;
        double sum = 0.0;
        for (int k = 0; k <= kmax; ++k)
            sum = fma(eps[k], zs[tid - k], sum);
        U[(size_t)row * T + tid] = sum;
    }
}

// Sequential LIF: v[t] = u[t] + sum_{j=31..1} ref[j]*s[t-j]; s = (v >= 10).
// hist bit (j-1) == spike at lag j. All f64.
__global__ __launch_bounds__(256) void spike_kernel(
    const double* __restrict__ U, float* __restrict__ S, int N, int T)
{
    __shared__ double refk[32];
    int tid = threadIdx.x;
    if (tid < 32) {
        double td = (double)tid;
        refk[tid] = -2.0 * 10.0 * (td / 2.0) * exp(1.0 - td / 2.0);
    }
    __syncthreads();

    int n = blockIdx.x * 256 + tid;
    if (n >= N) return;

    const double* u = U + (size_t)n * T;
    float*        s = S + (size_t)n * T;

    unsigned hist = 0u;   // bit (j-1) => spike at t-j
    for (int t = 0; t < T; ++t) {
        double r = 0.0;
        #pragma unroll
        for (int j = 31; j >= 1; --j)
            if ((hist >> (j - 1)) & 1u) r += refk[j];
        double v = u[t] + r;
        bool sp = (v >= 10.0);
        s[t] = sp ? 1.0f : 0.0f;
        hist = (hist << 1) | (sp ? 1u : 0u);
    }
}

// Final layer's spike output goes straight to f32 d_out.
// ---------------------------------------------------------------------------
extern "C" void kernel_launch(void* const* d_in, const int* in_sizes, int n_in,
                              void* d_out, int out_size, void* d_ws, size_t ws_size,
                              hipStream_t stream)
{
    const float* x  = (const float*)d_in[0];   // [8,16384,300]
    const float* W1 = (const float*)d_in[1];   // [410,16384]
    const float* W2 = (const float*)d_in[2];   // [240,410]
    const float* W3 = (const float*)d_in[3];   // [10,240]
    float* out = (float*)d_out;                // [8,10,300]

    const int B = 8, T = 300, F0 = 16384, O1 = 410, O2 = 240, O3 = 10;
    const size_t N1 = (size_t)B * O1 * T;      // 984000
    const size_t N2 = (size_t)B * O2 * T;      // 576000
    const size_t N3 = (size_t)B * O3 * T;      // 24000

    // f64 buffers first (8B-aligned), f32 spike buffers after.
    double* z1 = (double*)d_ws;
    double* u1 = z1 + N1;
    double* z2 = u1 + N1;
    double* u2 = z2 + N2;
    double* z3 = u2 + N2;
    double* u3 = z3 + N3;
    float*  s1 = (float*)(u3 + N3);
    float*  s2 = s1 + N1;
    // total: (2*N1+2*N2+2*N3)*8 + (N1+N2)*4 ≈ 31.6 MB

    dim3 blk(256);

    // layer 1
    gemm_kernel<<<dim3((T + 63) / 64, (O1 + 31) / 32, B), blk, 0, stream>>>(x, W1, z1, O1, F0, T);
    psp_kernel<<<dim3(B * O1), dim3(320), 0, stream>>>(z1, u1, T);
    spike_kernel<<<dim3((B * O1 + 255) / 256), blk, 0, stream>>>(u1, s1, B * O1, T);

    // layer 2
    gemm_kernel<<<dim3((T + 63) / 64, (O2 + 31) / 32, B), blk, 0, stream>>>(s1, W2, z2, O2, O1, T);
    psp_kernel<<<dim3(B * O2), dim3(320), 0, stream>>>(z2, u2, T);
    spike_kernel<<<dim3((B * O2 + 255) / 256), blk, 0, stream>>>(u2, s2, B * O2, T);

    // layer 3
    gemm_kernel<<<dim3((T + 63) / 64, (O3 + 31) / 32, B), blk, 0, stream>>>(s2, W3, z3, O3, O2, T);
    psp_kernel<<<dim3(B * O3), dim3(320), 0, stream>>>(z3, u3, T);
    spike_kernel<<<dim3((B * O3 + 255) / 256), blk, 0, stream>>>(u3, out, B * O3, T);
}

// Round 4
// 2249.533 us; speedup vs baseline: 2.2588x; 2.2588x over previous
//
#include <hip/hip_runtime.h>

// ---------------------------------------------------------------------------
// SLAYER SNN on MI355X.
// Layer 1 (the 93% cost): x is BINARY (~10% dense). Exact-integer sparse GEMM:
//   q[o,f] = rint(W1[o,f] * 2^31)  (i32)
//   z*2^31 = sum_{f active at (b,t)} q[o,f]   accumulated in i64 (EXACT,
//   order-independent -> atomic-built lists are safe & deterministic).
//   Error = quantization only (~6e-9 rms) vs spike margins ~4e-5.
// Layers 2/3: dense GEMM, f32 LDS staging, f64 accumulate (products exact
// since spikes are 0/1).
// psp+spike fused per row: u in LDS, lane 0 runs the sequential LIF with a
// 32-bit spike-history mask (ref[0]=0; bit j-1 <-> lag j).
// ---------------------------------------------------------------------------

#define OP 416        // padded O1 for QT rows (410 -> 416, 16B-aligned rows)
#define LCAP 2048     // list capacity per (b,t); mean 1638, sigma 38 -> 10.7 sigma

__global__ __launch_bounds__(256) void zero_cnt_kernel(int* cnt, int n) {
    int i = blockIdx.x * 256 + threadIdx.x;
    if (i < n) cnt[i] = 0;
}

// Build per-(b,t) active-f lists from x[b,f,t] (f32 0/1). Coalesced read.
__global__ __launch_bounds__(256) void encode_kernel(
    const float* __restrict__ X, unsigned short* __restrict__ lists,
    int* __restrict__ cnt, int total, int T, int F)
{
    int idx = blockIdx.x * 256 + threadIdx.x;
    if (idx >= total) return;
    if (X[idx] != 0.0f) {
        int t  = idx % T;
        int bf = idx / T;
        int f  = bf % F;
        int b  = bf / F;
        int col = b * T + t;
        int slot = atomicAdd(&cnt[col], 1);
        if (slot < LCAP) lists[(size_t)col * LCAP + slot] = (unsigned short)f;
    }
}

// QT[f][o] = rint(W1[o][f] * 2^31), i32, padded to OP cols. LDS-tiled transpose.
__global__ __launch_bounds__(256) void quant_transpose_kernel(
    const float* __restrict__ W, int* __restrict__ QT, int O, int F)
{
    __shared__ float tile[32][33];
    int f0 = blockIdx.x * 32;
    int o0 = blockIdx.y * 32;
    int tid = threadIdx.x;
    int c = tid & 31, r = tid >> 5;           // 8 rows per pass
    #pragma unroll
    for (int i = 0; i < 4; ++i) {
        int o = o0 + r + i * 8, f = f0 + c;
        tile[r + i * 8][c] = (o < O) ? W[(size_t)o * F + f] : 0.0f;
    }
    __syncthreads();
    #pragma unroll
    for (int i = 0; i < 4; ++i) {
        int fr = r + i * 8;                    // f within tile
        int o  = o0 + c;
        double w = (double)tile[c][fr] * 2147483648.0;   // exact scale
        QT[(size_t)(f0 + fr) * OP + o] = (int)__double2ll_rn(w);
    }
}

// z[b,o,t] = 2^-31 * sum_{f in list(b,t)} QT[f][o], i64 accumulate.
// Block = 128 threads, one (b,t) column; thread handles 4 consecutive o (int4).
__global__ __launch_bounds__(128) void sparse_gemm1_kernel(
    const int* __restrict__ QT, const unsigned short* __restrict__ lists,
    const int* __restrict__ cnt, double* __restrict__ Z, int O, int T)
{
    __shared__ int lf[LCAP];                   // element offsets f*OP
    int col = blockIdx.x;                      // b*T + t
    int b = col / T, t = col - b * T;
    int n = cnt[col]; if (n > LCAP) n = LCAP;

    const unsigned short* L = lists + (size_t)col * LCAP;
    for (int i = threadIdx.x; i < n; i += 128) lf[i] = (int)L[i] * OP;
    __syncthreads();

    int tid = threadIdx.x;
    if (tid * 4 >= OP) return;                 // threads 104..127 idle
    int o = tid * 4;
    const int* base = QT + o;

    long long a0 = 0, a1 = 0, a2 = 0, a3 = 0;
    int i = 0;
    for (; i + 4 <= n; i += 4) {
        int f0 = lf[i], f1 = lf[i + 1], f2 = lf[i + 2], f3 = lf[i + 3];
        int4 q0 = *(const int4*)(base + f0);
        int4 q1 = *(const int4*)(base + f1);
        int4 q2 = *(const int4*)(base + f2);
        int4 q3 = *(const int4*)(base + f3);
        a0 += q0.x; a1 += q0.y; a2 += q0.z; a3 += q0.w;
        a0 += q1.x; a1 += q1.y; a2 += q1.z; a3 += q1.w;
        a0 += q2.x; a1 += q2.y; a2 += q2.z; a3 += q2.w;
        a0 += q3.x; a1 += q3.y; a2 += q3.z; a3 += q3.w;
    }
    for (; i < n; ++i) {
        int4 q = *(const int4*)(base + lf[i]);
        a0 += q.x; a1 += q.y; a2 += q.z; a3 += q.w;
    }

    const double sc = 1.0 / 2147483648.0;      // 2^-31
    double* Zb = Z + ((size_t)b * O) * T + t;
    if (o + 0 < O) Zb[(size_t)(o + 0) * T] = (double)a0 * sc;
    if (o + 1 < O) Zb[(size_t)(o + 1) * T] = (double)a1 * sc;
    if (o + 2 < O) Zb[(size_t)(o + 2) * T] = (double)a2 * sc;
    if (o + 3 < O) Zb[(size_t)(o + 3) * T] = (double)a3 * sc;
}

// Dense small GEMM for layers 2/3: f32 LDS tiles, f64 accumulate.
__global__ __launch_bounds__(256) void gemm23_kernel(
    const float* __restrict__ X,   // [B,F,T] (0/1 spikes)
    const float* __restrict__ W,   // [O,F]
    double* __restrict__ Z,        // [B,O,T]
    int O, int F, int T)
{
    const int KT = 32;
    int b  = blockIdx.z;
    int o0 = blockIdx.y * 32;
    int t0 = blockIdx.x * 64;

    __shared__ float Ws[32][33];
    __shared__ float Xs[32][65];

    int tid = threadIdx.x;
    int ty  = tid >> 4;            // 0..15 (o)
    int tx  = tid & 15;            // 0..15 (t)

    double acc[2][4] = {{0,0,0,0},{0,0,0,0}};
    const float* Xb = X + (size_t)b * F * T;

    for (int f0 = 0; f0 < F; f0 += KT) {
        #pragma unroll
        for (int i = 0; i < 4; ++i) {
            int idx = i * 256 + tid;
            int r = idx >> 5, c = idx & 31;
            int o = o0 + r, f = f0 + c;
            Ws[r][c] = (o < O && f < F) ? W[(size_t)o * F + f] : 0.0f;
        }
        #pragma unroll
        for (int i = 0; i < 8; ++i) {
            int idx = i * 256 + tid;
            int r = idx >> 6, c = idx & 63;
            int f = f0 + r, t = t0 + c;
            Xs[r][c] = (f < F && t < T) ? Xb[(size_t)f * T + t] : 0.0f;
        }
        __syncthreads();

        #pragma unroll
        for (int kk = 0; kk < KT; ++kk) {
            float xv[4];
            #pragma unroll
            for (int j = 0; j < 4; ++j) xv[j] = Xs[kk][tx * 4 + j];
            #pragma unroll
            for (int i = 0; i < 2; ++i) {
                double wv = (double)Ws[ty * 2 + i][kk];
                #pragma unroll
                for (int j = 0; j < 4; ++j)
                    acc[i][j] = fma(wv, (double)xv[j], acc[i][j]);
            }
        }
        __syncthreads();
    }

    double* Zb = Z + (size_t)b * O * T;
    #pragma unroll
    for (int i = 0; i < 2; ++i) {
        int o = o0 + ty * 2 + i;
        if (o >= O) continue;
        #pragma unroll
        for (int j = 0; j < 4; ++j) {
            int t = t0 + tx * 4 + j;
            if (t < T) Zb[(size_t)o * T + t] = acc[i][j];
        }
    }
}

// Fused psp (100-tap alpha conv, f64) + sequential LIF spike, one block/row.
__global__ __launch_bounds__(320) void psp_spike_kernel(
    const double* __restrict__ Z, float* __restrict__ S, int T)
{
    __shared__ double eps[100];
    __shared__ double refk[32];
    __shared__ double zs[300];
    __shared__ double us[300];
    __shared__ float  ss[300];

    int row = blockIdx.x;
    int tid = threadIdx.x;

    if (tid < 100) {
        double td = (double)tid;
        eps[tid] = (td / 10.0) * exp(1.0 - td / 10.0);
    }
    if (tid < 32) {
        double td = (double)tid;
        refk[tid] = -2.0 * 10.0 * (td / 2.0) * exp(1.0 - td / 2.0);
    }
    if (tid < T) zs[tid] = Z[(size_t)row * T + tid];
    __syncthreads();

    if (tid < T) {
        int kmax = tid < 99 ? tid : 99;
        double sum = 0.0;
        for (int k = 0; k <= kmax; ++k)
            sum = fma(eps[k], zs[tid - k], sum);
        us[tid] = sum;
    }
    __syncthreads();

    if (tid == 0) {
        unsigned hist = 0u;        // bit (j-1) => spike at lag j
        for (int t = 0; t < T; ++t) {
            double r = 0.0;
            unsigned m = hist & 0x7FFFFFFFu;   // lags 1..31
            while (m) {
                int j = __ffs(m);              // bit idx+1 == lag
                r += refk[j];
                m &= m - 1;
            }
            double v = us[t] + r;
            bool sp = (v >= 10.0);
            ss[t] = sp ? 1.0f : 0.0f;
            hist = (hist << 1) | (sp ? 1u : 0u);
        }
    }
    __syncthreads();

    if (tid < T) S[(size_t)row * T + tid] = ss[tid];
}

// ---------------------------------------------------------------------------
extern "C" void kernel_launch(void* const* d_in, const int* in_sizes, int n_in,
                              void* d_out, int out_size, void* d_ws, size_t ws_size,
                              hipStream_t stream)
{
    const float* x  = (const float*)d_in[0];   // [8,16384,300]
    const float* W1 = (const float*)d_in[1];   // [410,16384]
    const float* W2 = (const float*)d_in[2];   // [240,410]
    const float* W3 = (const float*)d_in[3];   // [10,240]
    float* out = (float*)d_out;                // [8,10,300]

    const int B = 8, T = 300, F0 = 16384, O1 = 410, O2 = 240, O3 = 10;
    const size_t N1 = (size_t)B * O1 * T;      // 984000
    const size_t N2 = (size_t)B * O2 * T;      // 576000
    const size_t N3 = (size_t)B * O3 * T;      // 24000
    const int NCOL = B * T;                    // 2400

    // Workspace layout (QT first: 16B-aligned int4 rows; f64 next; then f32/u16)
    char* p = (char*)d_ws;
    int*            QT    = (int*)p;            p += (size_t)F0 * OP * 4;      // 27.3 MB
    double*         zu1   = (double*)p;         p += N1 * 8;                   //  7.9 MB
    double*         zu2   = (double*)p;         p += N2 * 8;                   //  4.6 MB
    double*         zu3   = (double*)p;         p += N3 * 8;                   //  0.2 MB
    unsigned short* lists = (unsigned short*)p; p += (size_t)NCOL * LCAP * 2;  //  9.8 MB
    float*          s1    = (float*)p;          p += N1 * 4;                   //  3.9 MB
    float*          s2    = (float*)p;          p += N2 * 4;                   //  2.3 MB
    int*            cnt   = (int*)p;            p += NCOL * 4;                 // ~10 KB
    // total ~56 MB

    // --- layer 1 (sparse exact-integer) ---
    zero_cnt_kernel<<<dim3((NCOL + 255) / 256), dim3(256), 0, stream>>>(cnt, NCOL);
    int total = B * F0 * T;
    encode_kernel<<<dim3((total + 255) / 256), dim3(256), 0, stream>>>(
        x, lists, cnt, total, T, F0);
    quant_transpose_kernel<<<dim3(F0 / 32, OP / 32), dim3(256), 0, stream>>>(
        W1, QT, O1, F0);
    sparse_gemm1_kernel<<<dim3(NCOL), dim3(128), 0, stream>>>(
        QT, lists, cnt, zu1, O1, T);
    psp_spike_kernel<<<dim3(B * O1), dim3(320), 0, stream>>>(zu1, s1, T);

    // --- layer 2 ---
    gemm23_kernel<<<dim3((T + 63) / 64, (O2 + 31) / 32, B), dim3(256), 0, stream>>>(
        s1, W2, zu2, O2, O1, T);
    psp_spike_kernel<<<dim3(B * O2), dim3(320), 0, stream>>>(zu2, s2, T);

    // --- layer 3 ---
    gemm23_kernel<<<dim3((T + 63) / 64, (O3 + 31) / 32, B), dim3(256), 0, stream>>>(
        s2, W3, zu3, O3, O2, T);
    psp_spike_kernel<<<dim3(B * O3), dim3(320), 0, stream>>>(zu3, out, T);
}

// Round 5
// 914.748 us; speedup vs baseline: 5.5547x; 2.4592x over previous
//
#include <hip/hip_runtime.h>

// ---------------------------------------------------------------------------
// SLAYER SNN on MI355X.
// Layer 1: x is BINARY (~10% dense). Exact-integer sparse GEMM:
//   q[o,f] = rint(W1[o,f] * 2^31) (i32); z*2^31 = sum_{active f} q[o,f] in i64
//   -> EXACT, order-independent, deterministic. Quant error ~6e-9 rms vs
//   spike-decision margins ~5e-5.
// Active sets come from a ballot-built bitmask (NO atomics — round-4's
// encode_kernel spent 1210us serializing 3.9M atomicAdds on 2400 counters).
// Layers 2/3: dense GEMM, f32 LDS tiles, f64 accumulate (spikes are 0/1 so
// products are exact).
// psp+spike fused per row: f64 alpha-kernel conv, lane-0 sequential LIF with
// 32-bit spike-history mask (ref[0]=0; bit j-1 <-> lag j).
// ---------------------------------------------------------------------------

#define OP 416        // padded O1 (410 -> 416) so QT rows are int4-tileable
#define LCAP 2048     // list capacity; n ~ Binom(16384,0.1): 1638 +/- 38 (10.7 sigma)
#define FW 256        // f-words per column: 16384/64

// ---------------------------------------------------------------------------
// cmask[col][fw] bit k = (X[b, fw*64+k, t] != 0), col = b*T + t.
// Block: 64f x 64t tile; coalesced global reads; LDS transpose; 1 ballot/col.
// Every word of cmask is written -> no init, re-poison safe, deterministic.
// ---------------------------------------------------------------------------
__global__ __launch_bounds__(256) void spike2mask_kernel(
    const float* __restrict__ X, unsigned long long* __restrict__ cmask,
    int F, int T)
{
    __shared__ float tile[64][65];
    int tt = blockIdx.x;               // t-tile (0..4)
    int fb = blockIdx.y;               // f-word index (0..255)
    int b  = blockIdx.z;
    int t0 = tt * 64, f0 = fb * 64;
    int tid = threadIdx.x;
    int w = tid >> 6, l = tid & 63;    // wave, lane

    const float* Xb = X + ((size_t)b * F + f0) * T;
    #pragma unroll
    for (int r = 0; r < 16; ++r) {
        int fl = w * 16 + r;
        int t  = t0 + l;
        tile[fl][l] = (t < T) ? Xb[(size_t)fl * T + t] : 0.0f;
    }
    __syncthreads();

    #pragma unroll
    for (int j = 0; j < 16; ++j) {
        int c = w * 16 + j;                                  // column within tile
        unsigned long long m = __ballot(tile[l][c] != 0.0f); // lane l <-> f0+l
        int t = t0 + c;
        if (l == 0 && t < T)
            cmask[(size_t)(b * T + t) * FW + fb] = m;
    }
}

// ---------------------------------------------------------------------------
// QT[f][o] = rint(W1[o][f] * 2^31), i32, padded to OP cols.
// ---------------------------------------------------------------------------
__global__ __launch_bounds__(256) void quant_transpose_kernel(
    const float* __restrict__ W, int* __restrict__ QT, int O, int F)
{
    __shared__ float tile[32][33];
    int f0 = blockIdx.x * 32;
    int o0 = blockIdx.y * 32;
    int tid = threadIdx.x;
    int c = tid & 31, r = tid >> 5;
    #pragma unroll
    for (int i = 0; i < 4; ++i) {
        int o = o0 + r + i * 8, f = f0 + c;
        tile[r + i * 8][c] = (o < O) ? W[(size_t)o * F + f] : 0.0f;
    }
    __syncthreads();
    #pragma unroll
    for (int i = 0; i < 4; ++i) {
        int fr = r + i * 8;
        int o  = o0 + c;
        double w = (double)tile[c][fr] * 2147483648.0;
        QT[(size_t)(f0 + fr) * OP + o] = (int)__double2ll_rn(w);
    }
}

// ---------------------------------------------------------------------------
// z[b,o,t] = 2^-31 * sum_{f in mask(b,t)} QT[f][o], i64 accumulate.
// Block = 128 threads, one column. Phase 1: rebuild ordered f-list from the
// 2KB column bitmask (popc + wave shfl_up prefix scan). Phase 2: int4 gather.
// ---------------------------------------------------------------------------
__global__ __launch_bounds__(128) void sparse_gemm1_kernel(
    const int* __restrict__ QT, const unsigned long long* __restrict__ cmask,
    double* __restrict__ Z, int O, int T)
{
    __shared__ int lf[LCAP];           // element offsets f*OP, ascending f
    __shared__ int wsum[2];

    int col = blockIdx.x;              // b*T + t
    int b = col / T, t = col - b * T;
    int tid = threadIdx.x;

    // --- build list from bitmask ---
    unsigned long long w0 = cmask[(size_t)col * FW + 2 * tid];
    unsigned long long w1 = cmask[(size_t)col * FW + 2 * tid + 1];
    int my = __popcll(w0) + __popcll(w1);

    int scan = my;                     // wave-inclusive scan
    #pragma unroll
    for (int d = 1; d < 64; d <<= 1) {
        int v = __shfl_up(scan, d);
        if ((tid & 63) >= d) scan += v;
    }
    if ((tid & 63) == 63) wsum[tid >> 6] = scan;
    __syncthreads();
    int off = ((tid >= 64) ? wsum[0] : 0) + scan - my;   // exclusive prefix
    int n = wsum[0] + wsum[1];

    unsigned long long m = w0;
    int fbase = (2 * tid) << 6;
    while (m) {
        int bit = __ffsll(m) - 1;
        if (off < LCAP) lf[off] = (fbase + bit) * OP;
        ++off; m &= m - 1;
    }
    m = w1; fbase = (2 * tid + 1) << 6;
    while (m) {
        int bit = __ffsll(m) - 1;
        if (off < LCAP) lf[off] = (fbase + bit) * OP;
        ++off; m &= m - 1;
    }
    __syncthreads();
    if (n > LCAP) n = LCAP;

    // --- gather + exact i64 accumulate ---
    if (tid * 4 >= OP) return;         // threads 104..127 done
    int o = tid * 4;
    const int* base = QT + o;

    long long a0 = 0, a1 = 0, a2 = 0, a3 = 0;
    int i = 0;
    for (; i + 4 <= n; i += 4) {
        int f0 = lf[i], f1 = lf[i + 1], f2 = lf[i + 2], f3 = lf[i + 3];
        int4 q0 = *(const int4*)(base + f0);
        int4 q1 = *(const int4*)(base + f1);
        int4 q2 = *(const int4*)(base + f2);
        int4 q3 = *(const int4*)(base + f3);
        a0 += q0.x; a1 += q0.y; a2 += q0.z; a3 += q0.w;
        a0 += q1.x; a1 += q1.y; a2 += q1.z; a3 += q1.w;
        a0 += q2.x; a1 += q2.y; a2 += q2.z; a3 += q2.w;
        a0 += q3.x; a1 += q3.y; a2 += q3.z; a3 += q3.w;
    }
    for (; i < n; ++i) {
        int4 q = *(const int4*)(base + lf[i]);
        a0 += q.x; a1 += q.y; a2 += q.z; a3 += q.w;
    }

    const double sc = 1.0 / 2147483648.0;   // 2^-31
    double* Zb = Z + ((size_t)b * O) * T + t;
    if (o + 0 < O) Zb[(size_t)(o + 0) * T] = (double)a0 * sc;
    if (o + 1 < O) Zb[(size_t)(o + 1) * T] = (double)a1 * sc;
    if (o + 2 < O) Zb[(size_t)(o + 2) * T] = (double)a2 * sc;
    if (o + 3 < O) Zb[(size_t)(o + 3) * T] = (double)a3 * sc;
}

// ---------------------------------------------------------------------------
// Dense small GEMM for layers 2/3: f32 LDS tiles, f64 accumulate.
// ---------------------------------------------------------------------------
__global__ __launch_bounds__(256) void gemm23_kernel(
    const float* __restrict__ X,   // [B,F,T] (0/1 spikes)
    const float* __restrict__ W,   // [O,F]
    double* __restrict__ Z,        // [B,O,T]
    int O, int F, int T)
{
    const int KT = 32;
    int b  = blockIdx.z;
    int o0 = blockIdx.y * 32;
    int t0 = blockIdx.x * 64;

    __shared__ float Ws[32][33];
    __shared__ float Xs[32][65];

    int tid = threadIdx.x;
    int ty  = tid >> 4;
    int tx  = tid & 15;

    double acc[2][4] = {{0,0,0,0},{0,0,0,0}};
    const float* Xb = X + (size_t)b * F * T;

    for (int f0 = 0; f0 < F; f0 += KT) {
        #pragma unroll
        for (int i = 0; i < 4; ++i) {
            int idx = i * 256 + tid;
            int r = idx >> 5, c = idx & 31;
            int o = o0 + r, f = f0 + c;
            Ws[r][c] = (o < O && f < F) ? W[(size_t)o * F + f] : 0.0f;
        }
        #pragma unroll
        for (int i = 0; i < 8; ++i) {
            int idx = i * 256 + tid;
            int r = idx >> 6, c = idx & 63;
            int f = f0 + r, t = t0 + c;
            Xs[r][c] = (f < F && t < T) ? Xb[(size_t)f * T + t] : 0.0f;
        }
        __syncthreads();

        #pragma unroll
        for (int kk = 0; kk < KT; ++kk) {
            float xv[4];
            #pragma unroll
            for (int j = 0; j < 4; ++j) xv[j] = Xs[kk][tx * 4 + j];
            #pragma unroll
            for (int i = 0; i < 2; ++i) {
                double wv = (double)Ws[ty * 2 + i][kk];
                #pragma unroll
                for (int j = 0; j < 4; ++j)
                    acc[i][j] = fma(wv, (double)xv[j], acc[i][j]);
            }
        }
        __syncthreads();
    }

    double* Zb = Z + (size_t)b * O * T;
    #pragma unroll
    for (int i = 0; i < 2; ++i) {
        int o = o0 + ty * 2 + i;
        if (o >= O) continue;
        #pragma unroll
        for (int j = 0; j < 4; ++j) {
            int t = t0 + tx * 4 + j;
            if (t < T) Zb[(size_t)o * T + t] = acc[i][j];
        }
    }
}

// ---------------------------------------------------------------------------
// Fused psp (100-tap alpha conv, f64) + sequential LIF spike, one block/row.
// ---------------------------------------------------------------------------
__global__ __launch_bounds__(320) void psp_spike_kernel(
    const double* __restrict__ Z, float* __restrict__ S, int T)
{
    __shared__ double eps[100];
    __shared__ double refk[32];
    __shared__ double zs[300];
    __shared__ double us[300];
    __shared__ float  ss[300];

    int row = blockIdx.x;
    int tid = threadIdx.x;

    if (tid < 100) {
        double td = (double)tid;
        eps[tid] = (td / 10.0) * exp(1.0 - td / 10.0);
    }
    if (tid < 32) {
        double td = (double)tid;
        refk[tid] = -2.0 * 10.0 * (td / 2.0) * exp(1.0 - td / 2.0);
    }
    if (tid < T) zs[tid] = Z[(size_t)row * T + tid];
    __syncthreads();

    if (tid < T) {
        int kmax = tid < 99 ? tid : 99;
        double sum = 0.0;
        for (int k = 0; k <= kmax; ++k)
            sum = fma(eps[k], zs[tid - k], sum);
        us[tid] = sum;
    }
    __syncthreads();

    if (tid == 0) {
        unsigned hist = 0u;        // bit (j-1) => spike at lag j
        for (int t = 0; t < T; ++t) {
            double r = 0.0;
            unsigned m = hist & 0x7FFFFFFFu;
            while (m) {
                int j = __ffs(m);
                r += refk[j];
                m &= m - 1;
            }
            double v = us[t] + r;
            bool sp = (v >= 10.0);
            ss[t] = sp ? 1.0f : 0.0f;
            hist = (hist << 1) | (sp ? 1u : 0u);
        }
    }
    __syncthreads();

    if (tid < T) S[(size_t)row * T + tid] = ss[tid];
}

// ---------------------------------------------------------------------------
extern "C" void kernel_launch(void* const* d_in, const int* in_sizes, int n_in,
                              void* d_out, int out_size, void* d_ws, size_t ws_size,
                              hipStream_t stream)
{
    const float* x  = (const float*)d_in[0];   // [8,16384,300]
    const float* W1 = (const float*)d_in[1];   // [410,16384]
    const float* W2 = (const float*)d_in[2];   // [240,410]
    const float* W3 = (const float*)d_in[3];   // [10,240]
    float* out = (float*)d_out;                // [8,10,300]

    const int B = 8, T = 300, F0 = 16384, O1 = 410, O2 = 240, O3 = 10;
    const size_t N1 = (size_t)B * O1 * T;      // 984000
    const size_t N2 = (size_t)B * O2 * T;      // 576000
    const size_t N3 = (size_t)B * O3 * T;      // 24000
    const int NCOL = B * T;                    // 2400

    char* p = (char*)d_ws;
    int*                QT    = (int*)p;                p += (size_t)F0 * OP * 4;    // 27.3 MB
    double*             zu1   = (double*)p;             p += N1 * 8;                 //  7.9 MB
    double*             zu2   = (double*)p;             p += N2 * 8;                 //  4.6 MB
    double*             zu3   = (double*)p;             p += N3 * 8;                 //  0.2 MB
    unsigned long long* cmask = (unsigned long long*)p; p += (size_t)NCOL * FW * 8;  //  4.9 MB
    float*              s1    = (float*)p;              p += N1 * 4;                 //  3.9 MB
    float*              s2    = (float*)p;              p += N2 * 4;                 //  2.3 MB
    // total ~51 MB

    // --- layer 1 (sparse exact-integer) ---
    spike2mask_kernel<<<dim3(5, FW, B), dim3(256), 0, stream>>>(x, cmask, F0, T);
    quant_transpose_kernel<<<dim3(F0 / 32, OP / 32), dim3(256), 0, stream>>>(W1, QT, O1, F0);
    sparse_gemm1_kernel<<<dim3(NCOL), dim3(128), 0, stream>>>(QT, cmask, zu1, O1, T);
    psp_spike_kernel<<<dim3(B * O1), dim3(320), 0, stream>>>(zu1, s1, T);

    // --- layer 2 ---
    gemm23_kernel<<<dim3((T + 63) / 64, (O2 + 31) / 32, B), dim3(256), 0, stream>>>(
        s1, W2, zu2, O2, O1, T);
    psp_spike_kernel<<<dim3(B * O2), dim3(320), 0, stream>>>(zu2, s2, T);

    // --- layer 3 ---
    gemm23_kernel<<<dim3((T + 63) / 64, (O3 + 31) / 32, B), dim3(256), 0, stream>>>(
        s2, W3, zu3, O3, O2, T);
    psp_spike_kernel<<<dim3(B * O3), dim3(320), 0, stream>>>(zu3, out, T);
}

// Round 6
// 778.397 us; speedup vs baseline: 6.5277x; 1.1752x over previous
//
#include <hip/hip_runtime.h>

// ---------------------------------------------------------------------------
// SLAYER SNN on MI355X — all-sparse exact-integer pipeline.
//   q[o,f] = rint(W[o,f]*2^s) (i32, s=31 for W1 since |W1|<0.3; s=29 for
//   W2/W3 since |W|~N(0,0.3^2) can exceed 1). z*2^s = sum over active f of
//   q[o,f], accumulated in i64 -> EXACT and order-independent. Chunked i64
//   partials sum exactly in psp. Quant error ~1e-8 vs spike margins ~1e-5.
// Layer-1 gather is XCD-chunked: f split into NCHUNK=8 chunks so each chunk's
// QT slice (3.4 MB) fits a 4 MB per-XCD L2; chunk = blockIdx.x & 7 rides the
// round-robin block->XCD mapping (perf heuristic only, correct regardless).
// Active sets ride ballot-built bitmasks end-to-end (no atomics anywhere).
// Spike phase: 1 thread per row, refk in registers, predicated 31-lag f64 sum
// (same summation order as the previous passing round).
// ---------------------------------------------------------------------------

#define B   8
#define T   300
#define F0  16384
#define O1  410
#define OP1 416
#define O2  240
#define OP2 240
#define O3  10
#define OP3 16
#define FW  256          // 64-bit words per layer-1 column mask
#define W1M 7            // words per layer-1 OUTPUT mask (410 -> 7)
#define W2M 4            // words per layer-2 OUTPUT mask (240 -> 4)
#define NCOLS (B*T)      // 2400
#define LCAP 2176

__global__ __launch_bounds__(256) void spike2mask_kernel(
    const float* __restrict__ X, unsigned long long* __restrict__ cmask)
{
    __shared__ float tile[64][65];
    int tt = blockIdx.x;
    int fb = blockIdx.y;
    int b  = blockIdx.z;
    int t0 = tt * 64, f0 = fb * 64;
    int tid = threadIdx.x;
    int w = tid >> 6, l = tid & 63;

    const float* Xb = X + ((size_t)b * F0 + f0) * T;
    #pragma unroll
    for (int r = 0; r < 16; ++r) {
        int fl = w * 16 + r;
        int t  = t0 + l;
        tile[fl][l] = (t < T) ? Xb[(size_t)fl * T + t] : 0.0f;
    }
    __syncthreads();

    #pragma unroll
    for (int j = 0; j < 16; ++j) {
        int c = w * 16 + j;
        unsigned long long m = __ballot(tile[l][c] != 0.0f);
        int t = t0 + c;
        if (l == 0 && t < T)
            cmask[(size_t)(b * T + t) * FW + fb] = m;
    }
}

__global__ __launch_bounds__(256) void quant_w1_kernel(
    const float* __restrict__ W, int* __restrict__ QT)
{
    __shared__ float tile[32][33];
    int f0 = blockIdx.x * 32;
    int o0 = blockIdx.y * 32;
    int tid = threadIdx.x;
    int c = tid & 31, r = tid >> 5;
    #pragma unroll
    for (int i = 0; i < 4; ++i) {
        int o = o0 + r + i * 8, f = f0 + c;
        tile[r + i * 8][c] = (o < O1) ? W[(size_t)o * F0 + f] : 0.0f;
    }
    __syncthreads();
    #pragma unroll
    for (int i = 0; i < 4; ++i) {
        int fr = r + i * 8;
        int o  = o0 + c;
        double w = (double)tile[c][fr] * 2147483648.0;   // 2^31
        QT[(size_t)(f0 + fr) * OP1 + o] = (int)__double2ll_rn(w);
    }
}

__global__ __launch_bounds__(256) void quant_small_kernel(
    const float* __restrict__ W, int* __restrict__ QT, int O, int F, int OPAD)
{
    int idx = blockIdx.x * 256 + threadIdx.x;
    if (idx >= F * OPAD) return;
    int f = idx / OPAD, o = idx - f * OPAD;
    double v = (o < O) ? (double)W[(size_t)o * F + f] : 0.0;
    QT[idx] = (int)__double2ll_rn(v * 536870912.0);      // 2^29
}

// ---------------------------------------------------------------------------
// Z[chunk][col][o] (i64) = sum_{f in mask words [chunk*CW, chunk*CW+CW)} QT[f][o]
// ---------------------------------------------------------------------------
__global__ __launch_bounds__(128) void sparse_gemm_kernel(
    const int* __restrict__ QT, const unsigned long long* __restrict__ cmask,
    long long* __restrict__ Z, int OPAD, int W, int CW, int cshift)
{
    __shared__ int lf[LCAP];
    __shared__ int wsum[2];

    int chunk = blockIdx.x & ((1 << cshift) - 1);
    int col   = blockIdx.x >> cshift;
    int tid   = threadIdx.x;

    int wbase = col * W + chunk * CW;
    unsigned long long w0 = (2 * tid     < CW) ? cmask[wbase + 2 * tid]     : 0ULL;
    unsigned long long w1 = (2 * tid + 1 < CW) ? cmask[wbase + 2 * tid + 1] : 0ULL;
    int my = __popcll(w0) + __popcll(w1);

    int scan = my;
    #pragma unroll
    for (int d = 1; d < 64; d <<= 1) {
        int v = __shfl_up(scan, d);
        if ((tid & 63) >= d) scan += v;
    }
    if ((tid & 63) == 63) wsum[tid >> 6] = scan;
    __syncthreads();
    int off = ((tid >= 64) ? wsum[0] : 0) + scan - my;
    int n = wsum[0] + wsum[1];

    int f0e = (chunk * CW + 2 * tid) * 64;           // first f of word w0
    unsigned long long m = w0;
    while (m) {
        int bit = __ffsll(m) - 1;
        if (off < LCAP) lf[off] = (f0e + bit) * OPAD;
        ++off; m &= m - 1;
    }
    m = w1; f0e += 64;                               // first f of word w1
    while (m) {
        int bit = __ffsll(m) - 1;
        if (off < LCAP) lf[off] = (f0e + bit) * OPAD;
        ++off; m &= m - 1;
    }
    __syncthreads();
    if (n > LCAP) n = LCAP;

    if (tid * 4 < OPAD) {
        int o = tid * 4;
        const int* bq = QT + o;
        long long a0 = 0, a1 = 0, a2 = 0, a3 = 0;
        int i = 0;
        for (; i + 4 <= n; i += 4) {
            int e0 = lf[i], e1 = lf[i + 1], e2 = lf[i + 2], e3 = lf[i + 3];
            int4 q0 = *(const int4*)(bq + e0);
            int4 q1 = *(const int4*)(bq + e1);
            int4 q2 = *(const int4*)(bq + e2);
            int4 q3 = *(const int4*)(bq + e3);
            a0 += q0.x; a1 += q0.y; a2 += q0.z; a3 += q0.w;
            a0 += q1.x; a1 += q1.y; a2 += q1.z; a3 += q1.w;
            a0 += q2.x; a1 += q2.y; a2 += q2.z; a3 += q2.w;
            a0 += q3.x; a1 += q3.y; a2 += q3.z; a3 += q3.w;
        }
        for (; i < n; ++i) {
            int4 q = *(const int4*)(bq + lf[i]);
            a0 += q.x; a1 += q.y; a2 += q.z; a3 += q.w;
        }
        long long* zb = Z + ((size_t)chunk * NCOLS + col) * OPAD + o;
        zb[0] = a0; zb[1] = a1; zb[2] = a2; zb[3] = a3;
    }
}

__global__ __launch_bounds__(320) void psp_kernel(
    const long long* __restrict__ Z, double* __restrict__ U,
    int OPAD, int O, int nchunk, double scale)
{
    __shared__ double zs[304];
    __shared__ double eps[100];
    int row = blockIdx.x;
    int b = row / O, o = row - b * O;
    int tid = threadIdx.x;

    if (tid < 100) {
        double td = (double)tid;
        eps[tid] = (td / 10.0) * exp(1.0 - td / 10.0);
    }
    if (tid < T) {
        long long s = 0;
        const long long* zp = Z + (size_t)(b * T + tid) * OPAD + o;
        for (int c = 0; c < nchunk; ++c)
            s += zp[(size_t)c * NCOLS * OPAD];
        zs[tid] = (double)s * scale;
    }
    __syncthreads();

    if (tid < T) {
        int kmax = tid < 99 ? tid : 99;
        double sum = 0.0;
        for (int k = 0; k <= kmax; ++k)
            sum = fma(eps[k], zs[tid - k], sum);
        U[(size_t)row * T + tid] = sum;
    }
}

__global__ __launch_bounds__(448) void spike_kernel(
    const double* __restrict__ U, unsigned long long* __restrict__ smask,
    float* __restrict__ sout, int O, int words)
{
    int b = blockIdx.x;
    int tid = threadIdx.x;
    int o = tid;
    bool active = o < O;
    int oc = active ? o : (O - 1);                 // clamp: no OOB reads
    const double* u = U + ((size_t)b * O + oc) * T;
    float* so = sout ? sout + ((size_t)b * O + oc) * T : (float*)0;

    double refk[32];
    #pragma unroll
    for (int j = 0; j < 32; ++j) {
        double td = (double)j;
        refk[j] = -2.0 * 10.0 * (td / 2.0) * exp(1.0 - td / 2.0);
    }

    unsigned hist = 0u;                            // bit (j-1) = spike at lag j
    for (int t = 0; t < T; ++t) {
        double r = 0.0;
        #pragma unroll
        for (int j = 1; j < 32; ++j)
            r += ((hist >> (j - 1)) & 1u) ? refk[j] : 0.0;
        double v = (active ? u[t] : -1.0e300) + r;
        bool sp = (v >= 10.0);
        unsigned long long bal = __ballot(sp);
        if (smask && (tid & 63) == 0)
            smask[((size_t)b * T + t) * words + (tid >> 6)] = bal;
        if (sout && active) so[t] = sp ? 1.0f : 0.0f;
        hist = (hist << 1) | (sp ? 1u : 0u);
    }
}

// ---------------------------------------------------------------------------
extern "C" void kernel_launch(void* const* d_in, const int* in_sizes, int n_in,
                              void* d_out, int out_size, void* d_ws, size_t ws_size,
                              hipStream_t stream)
{
    const float* x  = (const float*)d_in[0];
    const float* W1 = (const float*)d_in[1];
    const float* W2 = (const float*)d_in[2];
    const float* W3 = (const float*)d_in[3];
    float* out = (float*)d_out;

    const size_t N1 = (size_t)B * O1 * T;
    const size_t N2 = (size_t)B * O2 * T;
    const size_t N3 = (size_t)B * O3 * T;

    const size_t sz_QT     = (size_t)F0 * OP1 * 4;
    const size_t sz_plane  = (size_t)NCOLS * OP1 * 8;
    const size_t sz_u1     = N1 * 8;
    const size_t sz_z2     = (size_t)NCOLS * OP2 * 8;
    const size_t sz_u2     = N2 * 8;
    const size_t sz_z3     = (size_t)NCOLS * OP3 * 8;
    const size_t sz_u3     = N3 * 8;
    const size_t sz_cmask  = (size_t)NCOLS * FW * 8;
    const size_t sz_Q2T    = (size_t)O1 * OP2 * 4;
    const size_t sz_Q3T    = (size_t)O2 * OP3 * 4;
    const size_t sz_smask1 = (size_t)NCOLS * W1M * 8;
    const size_t sz_smask2 = (size_t)NCOLS * W2M * 8;

    size_t fixed = sz_QT + sz_u1 + sz_z2 + sz_u2 + sz_z3 + sz_u3 +
                   sz_cmask + sz_Q2T + sz_Q3T + sz_smask1 + sz_smask2;

    int cshift = 3;
    while (cshift > 0 && fixed + (sz_plane << cshift) > ws_size) --cshift;
    const int nchunk = 1 << cshift;
    const int CW = FW >> cshift;

    char* p = (char*)d_ws;
    int*                QT    = (int*)p;                p += sz_QT;
    long long*          zpart = (long long*)p;          p += sz_plane << cshift;
    double*             u1    = (double*)p;             p += sz_u1;
    long long*          z2    = (long long*)p;          p += sz_z2;
    double*             u2    = (double*)p;             p += sz_u2;
    long long*          z3    = (long long*)p;          p += sz_z3;
    double*             u3    = (double*)p;             p += sz_u3;
    unsigned long long* cmask = (unsigned long long*)p; p += sz_cmask;
    int*                Q2T   = (int*)p;                p += sz_Q2T;
    int*                Q3T   = (int*)p;                p += sz_Q3T;
    unsigned long long* smask1= (unsigned long long*)p; p += sz_smask1;
    unsigned long long* smask2= (unsigned long long*)p; p += sz_smask2;

    const double sc31 = 1.0 / 2147483648.0;
    const double sc29 = 1.0 / 536870912.0;

    spike2mask_kernel<<<dim3(5, FW, B), dim3(256), 0, stream>>>(x, cmask);
    quant_w1_kernel<<<dim3(F0 / 32, OP1 / 32), dim3(256), 0, stream>>>(W1, QT);
    quant_small_kernel<<<dim3((O1 * OP2 + 255) / 256), dim3(256), 0, stream>>>(
        W2, Q2T, O2, O1, OP2);
    quant_small_kernel<<<dim3((O2 * OP3 + 255) / 256), dim3(256), 0, stream>>>(
        W3, Q3T, O3, O2, OP3);

    sparse_gemm_kernel<<<dim3(NCOLS << cshift), dim3(128), 0, stream>>>(
        QT, cmask, zpart, OP1, FW, CW, cshift);
    psp_kernel<<<dim3(B * O1), dim3(320), 0, stream>>>(zpart, u1, OP1, O1, nchunk, sc31);
    spike_kernel<<<dim3(B), dim3(448), 0, stream>>>(u1, smask1, (float*)0, O1, W1M);

    sparse_gemm_kernel<<<dim3(NCOLS), dim3(128), 0, stream>>>(
        Q2T, smask1, z2, OP2, W1M, W1M, 0);
    psp_kernel<<<dim3(B * O2), dim3(320), 0, stream>>>(z2, u2, OP2, O2, 1, sc29);
    spike_kernel<<<dim3(B), dim3(256), 0, stream>>>(u2, smask2, (float*)0, O2, W2M);

    sparse_gemm_kernel<<<dim3(NCOLS), dim3(128), 0, stream>>>(
        Q3T, smask2, z3, OP3, W2M, W2M, 0);
    psp_kernel<<<dim3(B * O3), dim3(320), 0, stream>>>(z3, u3, OP3, O3, 1, sc29);
    spike_kernel<<<dim3(B), dim3(64), 0, stream>>>(u3, (unsigned long long*)0, out, O3, 0);
}

// Round 7
// 599.793 us; speedup vs baseline: 8.4715x; 1.2978x over previous
//
#include <hip/hip_runtime.h>

// ---------------------------------------------------------------------------
// SLAYER SNN on MI355X — all-sparse exact-integer pipeline.
//   q[o,f] = rint(W[o,f]*2^s) (i32; s=31 for W1, s=29 for W2/W3).
//   z*2^s = sum over active f of q[o,f] in i64 -> EXACT, order-independent.
// Layer-1 gather XCD-chunked (f split 8x so each QT slice fits 4MB per-XCD L2).
// Masks ride ballot-built bitmasks end-to-end (no atomics).
// This round: (1) reduce_t kernel fixes psp's 8x-strided zpart reads
// (coalesced chunk-reduce + LDS transpose, bit-identical values);
// (2) spike LIF via exact finite-window recurrence of ref[j]=-10e*j*alpha^j
// (E,G state + lag-31 eviction; fp delta ~1e-14 << margins ~1e-5);
// (3) sparse gather unrolled 8-deep for more outstanding loads.
// ---------------------------------------------------------------------------

#define B   8
#define T   300
#define F0  16384
#define O1  410
#define OP1 416
#define O2  240
#define OP2 240
#define O3  10
#define OP3 16
#define FW  256          // 64-bit words per layer-1 column mask
#define W1M 7            // words per layer-1 output mask (410 -> 7)
#define W2M 4            // words per layer-2 output mask (240 -> 4)
#define NCOLS (B*T)      // 2400
#define LCAP 2176

__global__ __launch_bounds__(256) void spike2mask_kernel(
    const float* __restrict__ X, unsigned long long* __restrict__ cmask)
{
    __shared__ float tile[64][65];
    int tt = blockIdx.x;
    int fb = blockIdx.y;
    int b  = blockIdx.z;
    int t0 = tt * 64, f0 = fb * 64;
    int tid = threadIdx.x;
    int w = tid >> 6, l = tid & 63;

    const float* Xb = X + ((size_t)b * F0 + f0) * T;
    #pragma unroll
    for (int r = 0; r < 16; ++r) {
        int fl = w * 16 + r;
        int t  = t0 + l;
        tile[fl][l] = (t < T) ? Xb[(size_t)fl * T + t] : 0.0f;
    }
    __syncthreads();

    #pragma unroll
    for (int j = 0; j < 16; ++j) {
        int c = w * 16 + j;
        unsigned long long m = __ballot(tile[l][c] != 0.0f);
        int t = t0 + c;
        if (l == 0 && t < T)
            cmask[(size_t)(b * T + t) * FW + fb] = m;
    }
}

__global__ __launch_bounds__(256) void quant_w1_kernel(
    const float* __restrict__ W, int* __restrict__ QT)
{
    __shared__ float tile[32][33];
    int f0 = blockIdx.x * 32;
    int o0 = blockIdx.y * 32;
    int tid = threadIdx.x;
    int c = tid & 31, r = tid >> 5;
    #pragma unroll
    for (int i = 0; i < 4; ++i) {
        int o = o0 + r + i * 8, f = f0 + c;
        tile[r + i * 8][c] = (o < O1) ? W[(size_t)o * F0 + f] : 0.0f;
    }
    __syncthreads();
    #pragma unroll
    for (int i = 0; i < 4; ++i) {
        int fr = r + i * 8;
        int o  = o0 + c;
        double w = (double)tile[c][fr] * 2147483648.0;   // 2^31
        QT[(size_t)(f0 + fr) * OP1 + o] = (int)__double2ll_rn(w);
    }
}

__global__ __launch_bounds__(256) void quant_small_kernel(
    const float* __restrict__ W, int* __restrict__ QT, int O, int F, int OPAD)
{
    int idx = blockIdx.x * 256 + threadIdx.x;
    if (idx >= F * OPAD) return;
    int f = idx / OPAD, o = idx - f * OPAD;
    double v = (o < O) ? (double)W[(size_t)o * F + f] : 0.0;
    QT[idx] = (int)__double2ll_rn(v * 536870912.0);      // 2^29
}

// ---------------------------------------------------------------------------
// Z[chunk][col][o] (i64) = sum_{f in mask words [chunk*CW, chunk*CW+CW)} QT[f][o]
// ---------------------------------------------------------------------------
__global__ __launch_bounds__(128) void sparse_gemm_kernel(
    const int* __restrict__ QT, const unsigned long long* __restrict__ cmask,
    long long* __restrict__ Z, int OPAD, int W, int CW, int cshift)
{
    __shared__ int lf[LCAP];
    __shared__ int wsum[2];

    int chunk = blockIdx.x & ((1 << cshift) - 1);
    int col   = blockIdx.x >> cshift;
    int tid   = threadIdx.x;

    int wbase = col * W + chunk * CW;
    unsigned long long w0 = (2 * tid     < CW) ? cmask[wbase + 2 * tid]     : 0ULL;
    unsigned long long w1 = (2 * tid + 1 < CW) ? cmask[wbase + 2 * tid + 1] : 0ULL;
    int my = __popcll(w0) + __popcll(w1);

    int scan = my;
    #pragma unroll
    for (int d = 1; d < 64; d <<= 1) {
        int v = __shfl_up(scan, d);
        if ((tid & 63) >= d) scan += v;
    }
    if ((tid & 63) == 63) wsum[tid >> 6] = scan;
    __syncthreads();
    int off = ((tid >= 64) ? wsum[0] : 0) + scan - my;
    int n = wsum[0] + wsum[1];

    int f0e = (chunk * CW + 2 * tid) * 64;           // first f of word w0
    unsigned long long m = w0;
    while (m) {
        int bit = __ffsll(m) - 1;
        if (off < LCAP) lf[off] = (f0e + bit) * OPAD;
        ++off; m &= m - 1;
    }
    m = w1; f0e += 64;                               // first f of word w1
    while (m) {
        int bit = __ffsll(m) - 1;
        if (off < LCAP) lf[off] = (f0e + bit) * OPAD;
        ++off; m &= m - 1;
    }
    __syncthreads();
    if (n > LCAP) n = LCAP;

    if (tid * 4 < OPAD) {
        int o = tid * 4;
        const int* bq = QT + o;
        long long a0 = 0, a1 = 0, a2 = 0, a3 = 0;
        int i = 0;
        for (; i + 8 <= n; i += 8) {
            int4 q0 = *(const int4*)(bq + lf[i]);
            int4 q1 = *(const int4*)(bq + lf[i + 1]);
            int4 q2 = *(const int4*)(bq + lf[i + 2]);
            int4 q3 = *(const int4*)(bq + lf[i + 3]);
            int4 q4 = *(const int4*)(bq + lf[i + 4]);
            int4 q5 = *(const int4*)(bq + lf[i + 5]);
            int4 q6 = *(const int4*)(bq + lf[i + 6]);
            int4 q7 = *(const int4*)(bq + lf[i + 7]);
            a0 += q0.x; a1 += q0.y; a2 += q0.z; a3 += q0.w;
            a0 += q1.x; a1 += q1.y; a2 += q1.z; a3 += q1.w;
            a0 += q2.x; a1 += q2.y; a2 += q2.z; a3 += q2.w;
            a0 += q3.x; a1 += q3.y; a2 += q3.z; a3 += q3.w;
            a0 += q4.x; a1 += q4.y; a2 += q4.z; a3 += q4.w;
            a0 += q5.x; a1 += q5.y; a2 += q5.z; a3 += q5.w;
            a0 += q6.x; a1 += q6.y; a2 += q6.z; a3 += q6.w;
            a0 += q7.x; a1 += q7.y; a2 += q7.z; a3 += q7.w;
        }
        for (; i < n; ++i) {
            int4 q = *(const int4*)(bq + lf[i]);
            a0 += q.x; a1 += q.y; a2 += q.z; a3 += q.w;
        }
        long long* zb = Z + ((size_t)chunk * NCOLS + col) * OPAD + o;
        zb[0] = a0; zb[1] = a1; zb[2] = a2; zb[3] = a3;
    }
}

// ---------------------------------------------------------------------------
// zt[b][o][t] (f64, scaled) = scale * sum_c Z[c][b*T+t][o].
// Coalesced reads (consecutive o), LDS transpose, coalesced writes (consec t).
// Ascending-c summation: bit-identical to previous rounds' psp chunk-sum.
// ---------------------------------------------------------------------------
__global__ __launch_bounds__(256) void reduce_t_kernel(
    const long long* __restrict__ Z, double* __restrict__ ZT,
    int OPAD, int O, int nchunk, double scale)
{
    __shared__ double tile[64][65];
    int t0 = blockIdx.x * 64;
    int o0 = blockIdx.y * 64;
    int b  = blockIdx.z;
    int tid = threadIdx.x;
    int tx = tid & 63, ty = tid >> 6;

    #pragma unroll 4
    for (int r = 0; r < 16; ++r) {
        int t = t0 + ty * 16 + r;
        int o = o0 + tx;
        long long s = 0;
        if (t < T && o < OPAD) {
            const long long* zp = Z + ((size_t)(b * T + t)) * OPAD + o;
            for (int c = 0; c < nchunk; ++c)
                s += zp[(size_t)c * NCOLS * OPAD];
        }
        tile[ty * 16 + r][tx] = (double)s * scale;
    }
    __syncthreads();
    #pragma unroll 4
    for (int r = 0; r < 16; ++r) {
        int o = o0 + ty * 16 + r;
        int t = t0 + tx;
        if (o < O && t < T)
            ZT[((size_t)b * O + o) * T + t] = tile[tx][ty * 16 + r];
    }
}

// ---------------------------------------------------------------------------
// psp: u[row][t] = sum_k eps[k]*z[row][t-k]; row contiguous; in-place safe
// (row fully staged in LDS before any write).
// ---------------------------------------------------------------------------
__global__ __launch_bounds__(320) void psp_kernel(
    const double* __restrict__ Zin, double* __restrict__ U)
{
    __shared__ double zs[304];
    __shared__ double eps[100];
    int row = blockIdx.x;
    int tid = threadIdx.x;

    if (tid < 100) {
        double td = (double)tid;
        eps[tid] = (td / 10.0) * exp(1.0 - td / 10.0);
    }
    if (tid < T) zs[tid] = Zin[(size_t)row * T + tid];
    __syncthreads();

    if (tid < T) {
        int kmax = tid < 99 ? tid : 99;
        double sum = 0.0;
        for (int k = 0; k <= kmax; ++k)
            sum = fma(eps[k], zs[tid - k], sum);
        U[(size_t)row * T + tid] = sum;
    }
}

// ---------------------------------------------------------------------------
// Spike LIF via exact finite-window recurrence:
//   ref[j] = -10e * j * alpha^j, alpha=e^{-1/2};  r_t = -10e * G_t
//   E_t = sum_{j=1..31} alpha^j s_{t-j};  G_t = sum_{j=1..31} j alpha^j s_{t-j}
//   E' = a(sN + E - A31*s31);  G' = a(sN + (G - 31*A31*s31) + (E - A31*s31))
// Block = 64 threads = one 64-o word of one b; u staged in LDS per 64-t chunk.
// ---------------------------------------------------------------------------
__global__ __launch_bounds__(64) void spike_kernel(
    const double* __restrict__ U, unsigned long long* __restrict__ smask,
    float* __restrict__ sout, int O, int words)
{
    __shared__ double us[64][65];
    int w = blockIdx.x, b = blockIdx.y;
    int lane = threadIdx.x;
    int o = w * 64 + lane;
    bool active = o < O;

    const double alpha = exp(-0.5);
    const double A31   = exp(-15.5);          // alpha^31
    const double c0    = -10.0 * exp(1.0);    // -10e

    double E = 0.0, G = 0.0;
    unsigned hist = 0u;                       // bit k = spike at lag k+1

    float* so = (sout && active) ? sout + ((size_t)b * O + o) * T : (float*)0;

    for (int t0 = 0; t0 < T; t0 += 64) {
        int cl = (T - t0 < 64) ? (T - t0) : 64;
        __syncthreads();
        for (int r = 0; r < 64; ++r) {
            int orow = w * 64 + r;
            if (orow >= O) orow = O - 1;
            if (lane < cl)
                us[r][lane] = U[((size_t)b * O + orow) * T + t0 + lane];
        }
        __syncthreads();

        for (int tl = 0; tl < cl; ++tl) {
            double uval = active ? us[lane][tl] : -1.0e300;
            double v = uval + c0 * G;
            bool sp = (v >= 10.0);
            unsigned long long bal = __ballot(sp);
            if (smask && lane == 0)
                smask[((size_t)b * T + t0 + tl) * words + w] = bal;
            if (so) so[t0 + tl] = sp ? 1.0f : 0.0f;

            double sN  = sp ? 1.0 : 0.0;
            double s31 = ((hist >> 30) & 1u) ? 1.0 : 0.0;
            double Em  = E - A31 * s31;
            double Gm  = G - 31.0 * A31 * s31;
            G = alpha * (sN + Gm + Em);
            E = alpha * (sN + Em);
            hist = (hist << 1) | (sp ? 1u : 0u);
        }
    }
}

// ---------------------------------------------------------------------------
extern "C" void kernel_launch(void* const* d_in, const int* in_sizes, int n_in,
                              void* d_out, int out_size, void* d_ws, size_t ws_size,
                              hipStream_t stream)
{
    const float* x  = (const float*)d_in[0];
    const float* W1 = (const float*)d_in[1];
    const float* W2 = (const float*)d_in[2];
    const float* W3 = (const float*)d_in[3];
    float* out = (float*)d_out;

    const size_t N1 = (size_t)B * O1 * T;
    const size_t N2 = (size_t)B * O2 * T;
    const size_t N3 = (size_t)B * O3 * T;

    const size_t sz_QT     = (size_t)F0 * OP1 * 4;
    const size_t sz_plane  = (size_t)NCOLS * OP1 * 8;
    const size_t sz_zt1    = N1 * 8;
    const size_t sz_z2     = (size_t)NCOLS * OP2 * 8;
    const size_t sz_zt2    = N2 * 8;
    const size_t sz_z3     = (size_t)NCOLS * OP3 * 8;
    const size_t sz_zt3    = N3 * 8;
    const size_t sz_cmask  = (size_t)NCOLS * FW * 8;
    const size_t sz_Q2T    = (size_t)O1 * OP2 * 4;
    const size_t sz_Q3T    = (size_t)O2 * OP3 * 4;
    const size_t sz_smask1 = (size_t)NCOLS * W1M * 8;
    const size_t sz_smask2 = (size_t)NCOLS * W2M * 8;

    size_t fixed = sz_QT + sz_zt1 + sz_z2 + sz_zt2 + sz_z3 + sz_zt3 +
                   sz_cmask + sz_Q2T + sz_Q3T + sz_smask1 + sz_smask2;

    int cshift = 3;
    while (cshift > 0 && fixed + (sz_plane << cshift) > ws_size) --cshift;
    const int nchunk = 1 << cshift;
    const int CW = FW >> cshift;

    char* p = (char*)d_ws;
    int*                QT    = (int*)p;                p += sz_QT;
    long long*          zpart = (long long*)p;          p += sz_plane << cshift;
    double*             zt1   = (double*)p;             p += sz_zt1;   // aliases u1
    long long*          z2    = (long long*)p;          p += sz_z2;
    double*             zt2   = (double*)p;             p += sz_zt2;   // aliases u2
    long long*          z3    = (long long*)p;          p += sz_z3;
    double*             zt3   = (double*)p;             p += sz_zt3;   // aliases u3
    unsigned long long* cmask = (unsigned long long*)p; p += sz_cmask;
    int*                Q2T   = (int*)p;                p += sz_Q2T;
    int*                Q3T   = (int*)p;                p += sz_Q3T;
    unsigned long long* smask1= (unsigned long long*)p; p += sz_smask1;
    unsigned long long* smask2= (unsigned long long*)p; p += sz_smask2;

    const double sc31 = 1.0 / 2147483648.0;
    const double sc29 = 1.0 / 536870912.0;

    // --- prep ---
    spike2mask_kernel<<<dim3(5, FW, B), dim3(256), 0, stream>>>(x, cmask);
    quant_w1_kernel<<<dim3(F0 / 32, OP1 / 32), dim3(256), 0, stream>>>(W1, QT);
    quant_small_kernel<<<dim3((O1 * OP2 + 255) / 256), dim3(256), 0, stream>>>(
        W2, Q2T, O2, O1, OP2);
    quant_small_kernel<<<dim3((O2 * OP3 + 255) / 256), dim3(256), 0, stream>>>(
        W3, Q3T, O3, O2, OP3);

    // --- layer 1 ---
    sparse_gemm_kernel<<<dim3(NCOLS << cshift), dim3(128), 0, stream>>>(
        QT, cmask, zpart, OP1, FW, CW, cshift);
    reduce_t_kernel<<<dim3(5, 7, B), dim3(256), 0, stream>>>(
        zpart, zt1, OP1, O1, nchunk, sc31);
    psp_kernel<<<dim3(B * O1), dim3(320), 0, stream>>>(zt1, zt1);
    spike_kernel<<<dim3(W1M, B), dim3(64), 0, stream>>>(zt1, smask1, (float*)0, O1, W1M);

    // --- layer 2 ---
    sparse_gemm_kernel<<<dim3(NCOLS), dim3(128), 0, stream>>>(
        Q2T, smask1, z2, OP2, W1M, W1M, 0);
    reduce_t_kernel<<<dim3(5, 4, B), dim3(256), 0, stream>>>(
        z2, zt2, OP2, O2, 1, sc29);
    psp_kernel<<<dim3(B * O2), dim3(320), 0, stream>>>(zt2, zt2);
    spike_kernel<<<dim3(W2M, B), dim3(64), 0, stream>>>(zt2, smask2, (float*)0, O2, W2M);

    // --- layer 3 ---
    sparse_gemm_kernel<<<dim3(NCOLS), dim3(128), 0, stream>>>(
        Q3T, smask2, z3, OP3, W2M, W2M, 0);
    reduce_t_kernel<<<dim3(5, 1, B), dim3(256), 0, stream>>>(
        z3, zt3, OP3, O3, 1, sc29);
    psp_kernel<<<dim3(B * O3), dim3(320), 0, stream>>>(zt3, zt3);
    spike_kernel<<<dim3(1, B), dim3(64), 0, stream>>>(zt3, (unsigned long long*)0, out, O3, 0);
}

// Round 8
// 583.609 us; speedup vs baseline: 8.7065x; 1.0277x over previous
//
#include <hip/hip_runtime.h>

// ---------------------------------------------------------------------------
// SLAYER SNN on MI355X — all-sparse exact-integer pipeline.
//   q[o,f] = rint(W[o,f]*2^s) (i32; s=27 for W1, s=26 for W2/W3).
//   z*2^s = sum over active f of q[o,f], accumulated in i32 per chunk
//   (partials fit i32 at >=12 sigma), partials summed in i64 -> EXACT,
//   order-independent. Quant error rms ~1e-7 vs spike margins ~1e-5.
// Layer-1 gather XCD-chunked (f split 8x so each QT slice fits 4MB per-XCD L2).
// Gather addressing is SCALAR: list indices are block-uniform ->
// readfirstlane puts address math on the SALU pipe (VALU only does adds).
// Masks ride ballot-built bitmasks end-to-end (no atomics).
// redpsp fuses chunk-reduce + 100-tap alpha conv (16 reg accumulators).
// Spike LIF via exact finite-window recurrence (E,G state + lag-31 evict).
// ---------------------------------------------------------------------------

#define B   8
#define T   300
#define F0  16384
#define O1  410
#define OP1 416
#define O2  240
#define OP2 240
#define O3  10
#define OP3 16
#define FW  256          // 64-bit words per layer-1 column mask
#define W1M 7            // words per layer-1 output mask (410 -> 7)
#define W2M 4            // words per layer-2 output mask (240 -> 4)
#define NCOLS (B*T)      // 2400
#define LCAP 2048        // >= max bits per chunk (CW=32 words -> 2048)

__global__ __launch_bounds__(256) void spike2mask_kernel(
    const float* __restrict__ X, unsigned long long* __restrict__ cmask)
{
    __shared__ float tile[64][72];     // 72: float4-aligned, 2-way-bank-free
    int tt = blockIdx.x;
    int fb = blockIdx.y;
    int b  = blockIdx.z;
    int t0 = tt * 64, f0 = fb * 64;
    int tid = threadIdx.x;

    const float* Xb = X + ((size_t)b * F0 + f0) * T;
    int fl = tid >> 4;                 // 0..15
    int tq = (tid & 15) * 4;           // t-quad
    #pragma unroll
    for (int i = 0; i < 4; ++i) {
        int fr = fl + i * 16;
        int t  = t0 + tq;
        float4 v = make_float4(0.f, 0.f, 0.f, 0.f);
        if (t + 3 < T) v = *(const float4*)(Xb + (size_t)fr * T + t);
        *(float4*)&tile[fr][tq] = v;   // t>=297..299 handled below never needed: T%4==0 -> t<300 means t+3<300
    }
    __syncthreads();

    int w = tid >> 6, l = tid & 63;
    #pragma unroll
    for (int j = 0; j < 16; ++j) {
        int c = w * 16 + j;
        unsigned long long m = __ballot(tile[l][c] != 0.0f);
        int t = t0 + c;
        if (l == 0 && t < T)
            cmask[(size_t)(b * T + t) * FW + fb] = m;
    }
}

__global__ __launch_bounds__(256) void quant_w1_kernel(
    const float* __restrict__ W, int* __restrict__ QT)
{
    __shared__ float tile[32][33];
    int f0 = blockIdx.x * 32;
    int o0 = blockIdx.y * 32;
    int tid = threadIdx.x;
    int c = tid & 31, r = tid >> 5;
    #pragma unroll
    for (int i = 0; i < 4; ++i) {
        int o = o0 + r + i * 8, f = f0 + c;
        tile[r + i * 8][c] = (o < O1) ? W[(size_t)o * F0 + f] : 0.0f;
    }
    __syncthreads();
    #pragma unroll
    for (int i = 0; i < 4; ++i) {
        int fr = r + i * 8;
        int o  = o0 + c;
        double w = (double)tile[c][fr] * 134217728.0;    // 2^27
        QT[(size_t)(f0 + fr) * OP1 + o] = (int)__double2ll_rn(w);
    }
}

__global__ __launch_bounds__(256) void quant_small_kernel(
    const float* __restrict__ W, int* __restrict__ QT, int O, int F, int OPAD)
{
    int idx = blockIdx.x * 256 + threadIdx.x;
    if (idx >= F * OPAD) return;
    int f = idx / OPAD, o = idx - f * OPAD;
    double v = (o < O) ? (double)W[(size_t)o * F + f] : 0.0;
    QT[idx] = (int)__double2ll_rn(v * 67108864.0);       // 2^26
}

// ---------------------------------------------------------------------------
// Z[chunk][col][o] (i32) = sum_{f in mask words [chunk*CW, chunk*CW+CW)} QT[f][o]
// ---------------------------------------------------------------------------
__global__ __launch_bounds__(128) void sparse_gemm_kernel(
    const int* __restrict__ QT, const unsigned long long* __restrict__ cmask,
    int* __restrict__ Z, int OPAD, int W, int CW, int cshift)
{
    __shared__ int lf[LCAP];
    __shared__ int wsum[2];

    int chunk = blockIdx.x & ((1 << cshift) - 1);
    int col   = blockIdx.x >> cshift;
    int tid   = threadIdx.x;

    int wbase = col * W + chunk * CW;
    unsigned long long w0 = (2 * tid     < CW) ? cmask[wbase + 2 * tid]     : 0ULL;
    unsigned long long w1 = (2 * tid + 1 < CW) ? cmask[wbase + 2 * tid + 1] : 0ULL;
    int my = __popcll(w0) + __popcll(w1);

    int scan = my;
    #pragma unroll
    for (int d = 1; d < 64; d <<= 1) {
        int v = __shfl_up(scan, d);
        if ((tid & 63) >= d) scan += v;
    }
    if ((tid & 63) == 63) wsum[tid >> 6] = scan;
    __syncthreads();
    int off = ((tid >= 64) ? wsum[0] : 0) + scan - my;
    int n = wsum[0] + wsum[1];

    int f0e = (chunk * CW + 2 * tid) * 64;           // first f of word w0
    unsigned long long m = w0;
    while (m) {
        int bit = __ffsll(m) - 1;
        if (off < LCAP) lf[off] = (f0e + bit) * OPAD;
        ++off; m &= m - 1;
    }
    m = w1; f0e += 64;
    while (m) {
        int bit = __ffsll(m) - 1;
        if (off < LCAP) lf[off] = (f0e + bit) * OPAD;
        ++off; m &= m - 1;
    }
    __syncthreads();
    if (n > LCAP) n = LCAP;

    if (tid * 4 < OPAD) {
        int o = tid * 4;
        const int* bq = QT + o;
        int a0 = 0, a1 = 0, a2 = 0, a3 = 0;
        int i = 0;
        for (; i + 8 <= n; i += 8) {
            int4 ia = *(const int4*)&lf[i];          // ds_read_b128
            int4 ib = *(const int4*)&lf[i + 4];
            int e0 = __builtin_amdgcn_readfirstlane(ia.x);
            int e1 = __builtin_amdgcn_readfirstlane(ia.y);
            int e2 = __builtin_amdgcn_readfirstlane(ia.z);
            int e3 = __builtin_amdgcn_readfirstlane(ia.w);
            int e4 = __builtin_amdgcn_readfirstlane(ib.x);
            int e5 = __builtin_amdgcn_readfirstlane(ib.y);
            int e6 = __builtin_amdgcn_readfirstlane(ib.z);
            int e7 = __builtin_amdgcn_readfirstlane(ib.w);
            int4 q0 = *(const int4*)(bq + e0);
            int4 q1 = *(const int4*)(bq + e1);
            int4 q2 = *(const int4*)(bq + e2);
            int4 q3 = *(const int4*)(bq + e3);
            int4 q4 = *(const int4*)(bq + e4);
            int4 q5 = *(const int4*)(bq + e5);
            int4 q6 = *(const int4*)(bq + e6);
            int4 q7 = *(const int4*)(bq + e7);
            a0 += q0.x; a1 += q0.y; a2 += q0.z; a3 += q0.w;
            a0 += q1.x; a1 += q1.y; a2 += q1.z; a3 += q1.w;
            a0 += q2.x; a1 += q2.y; a2 += q2.z; a3 += q2.w;
            a0 += q3.x; a1 += q3.y; a2 += q3.z; a3 += q3.w;
            a0 += q4.x; a1 += q4.y; a2 += q4.z; a3 += q4.w;
            a0 += q5.x; a1 += q5.y; a2 += q5.z; a3 += q5.w;
            a0 += q6.x; a1 += q6.y; a2 += q6.z; a3 += q6.w;
            a0 += q7.x; a1 += q7.y; a2 += q7.z; a3 += q7.w;
        }
        for (; i < n; ++i) {
            int e = __builtin_amdgcn_readfirstlane(lf[i]);
            int4 q = *(const int4*)(bq + e);
            a0 += q.x; a1 += q.y; a2 += q.z; a3 += q.w;
        }
        int* zb = Z + ((size_t)chunk * NCOLS + col) * OPAD + o;
        *(int4*)zb = make_int4(a0, a1, a2, a3);
    }
}

// ---------------------------------------------------------------------------
// Fused chunk-reduce + psp conv. Block = (o-group of 16, b).
// zs[o][t] = scale * sum_c Z[c][b*T+t][o]  (i64 reduce, exact);
// u[b][o][t] = sum_k eps[k] * zs[o][t-k]   (16 register accumulators).
// ---------------------------------------------------------------------------
__global__ __launch_bounds__(320) void redpsp_kernel(
    const int* __restrict__ Z, double* __restrict__ U,
    int OPAD, int O, int nchunk, double scale)
{
    __shared__ double zs[16][304];
    __shared__ double eps[100];
    int og = blockIdx.x, b = blockIdx.y;
    int o0 = og * 16;
    int tid = threadIdx.x;

    if (tid < 100) {
        double td = (double)tid;
        eps[tid] = (td / 10.0) * exp(1.0 - td / 10.0);
    }
    int ol = tid & 15, tg = tid >> 4;            // tg 0..19
    for (int t = tg; t < T; t += 20) {
        const int* zp = Z + ((size_t)(b * T + t)) * OPAD + o0 + ol;
        long long s = 0;
        for (int c = 0; c < nchunk; ++c)
            s += zp[(size_t)c * NCOLS * OPAD];
        zs[ol][t] = (double)s * scale;
    }
    __syncthreads();

    if (tid < T) {
        double sum[16];
        #pragma unroll
        for (int o = 0; o < 16; ++o) sum[o] = 0.0;
        int kmax = tid < 99 ? tid : 99;
        for (int k = 0; k <= kmax; ++k) {
            double e = eps[k];
            #pragma unroll
            for (int o = 0; o < 16; ++o)
                sum[o] = fma(e, zs[o][tid - k], sum[o]);
        }
        #pragma unroll
        for (int o = 0; o < 16; ++o) {
            int oo = o0 + o;
            if (oo < O) U[((size_t)b * O + oo) * T + tid] = sum[o];
        }
    }
}

// ---------------------------------------------------------------------------
// Spike LIF via exact finite-window recurrence:
//   ref[j] = -10e * j * alpha^j, alpha=e^{-1/2};  r_t = -10e * G_t
//   E' = a(sN + E - A31*s31);  G' = a(sN + (G - 31*A31*s31) + (E - A31*s31))
// Block = 64 threads = one 64-o word of one b; u staged in LDS per 64-t chunk.
// ---------------------------------------------------------------------------
__global__ __launch_bounds__(64) void spike_kernel(
    const double* __restrict__ U, unsigned long long* __restrict__ smask,
    float* __restrict__ sout, int O, int words)
{
    __shared__ double us[64][65];
    int w = blockIdx.x, b = blockIdx.y;
    int lane = threadIdx.x;
    int o = w * 64 + lane;
    bool active = o < O;

    const double alpha = exp(-0.5);
    const double A31   = exp(-15.5);
    const double c0    = -10.0 * exp(1.0);

    double E = 0.0, G = 0.0;
    unsigned hist = 0u;                       // bit k = spike at lag k+1

    float* so = (sout && active) ? sout + ((size_t)b * O + o) * T : (float*)0;

    for (int t0 = 0; t0 < T; t0 += 64) {
        int cl = (T - t0 < 64) ? (T - t0) : 64;
        __syncthreads();
        for (int r = 0; r < 64; ++r) {
            int orow = w * 64 + r;
            if (orow >= O) orow = O - 1;
            if (lane < cl)
                us[r][lane] = U[((size_t)b * O + orow) * T + t0 + lane];
        }
        __syncthreads();

        for (int tl = 0; tl < cl; ++tl) {
            double uval = active ? us[lane][tl] : -1.0e300;
            double v = uval + c0 * G;
            bool sp = (v >= 10.0);
            unsigned long long bal = __ballot(sp);
            if (smask && lane == 0)
                smask[((size_t)b * T + t0 + tl) * words + w] = bal;
            if (so) so[t0 + tl] = sp ? 1.0f : 0.0f;

            double sN  = sp ? 1.0 : 0.0;
            double s31 = ((hist >> 30) & 1u) ? 1.0 : 0.0;
            double Em  = E - A31 * s31;
            double Gm  = G - 31.0 * A31 * s31;
            G = alpha * (sN + Gm + Em);
            E = alpha * (sN + Em);
            hist = (hist << 1) | (sp ? 1u : 0u);
        }
    }
}

// ---------------------------------------------------------------------------
extern "C" void kernel_launch(void* const* d_in, const int* in_sizes, int n_in,
                              void* d_out, int out_size, void* d_ws, size_t ws_size,
                              hipStream_t stream)
{
    const float* x  = (const float*)d_in[0];
    const float* W1 = (const float*)d_in[1];
    const float* W2 = (const float*)d_in[2];
    const float* W3 = (const float*)d_in[3];
    float* out = (float*)d_out;

    const size_t N1 = (size_t)B * O1 * T;
    const size_t N2 = (size_t)B * O2 * T;
    const size_t N3 = (size_t)B * O3 * T;

    const size_t sz_QT     = (size_t)F0 * OP1 * 4;          // 27.3 MB
    const size_t sz_zpart  = (size_t)8 * NCOLS * OP1 * 4;   // 16.0 MB (8 chunks, i32)
    const size_t sz_u1     = N1 * 8;
    const size_t sz_z2     = (size_t)NCOLS * OP2 * 4;
    const size_t sz_u2     = N2 * 8;
    const size_t sz_z3     = (size_t)NCOLS * OP3 * 4;
    const size_t sz_u3     = N3 * 8;
    const size_t sz_cmask  = (size_t)NCOLS * FW * 8;
    const size_t sz_Q2T    = (size_t)O1 * OP2 * 4;
    const size_t sz_Q3T    = (size_t)O2 * OP3 * 4;
    const size_t sz_smask1 = (size_t)NCOLS * W1M * 8;
    const size_t sz_smask2 = (size_t)NCOLS * W2M * 8;

    char* p = (char*)d_ws;
    int*                QT    = (int*)p;                p += sz_QT;
    int*                zpart = (int*)p;                p += sz_zpart;
    double*             u1    = (double*)p;             p += sz_u1;
    int*                z2    = (int*)p;                p += sz_z2;
    double*             u2    = (double*)p;             p += sz_u2;
    int*                z3    = (int*)p;                p += sz_z3;
    double*             u3    = (double*)p;             p += sz_u3;
    unsigned long long* cmask = (unsigned long long*)p; p += sz_cmask;
    int*                Q2T   = (int*)p;                p += sz_Q2T;
    int*                Q3T   = (int*)p;                p += sz_Q3T;
    unsigned long long* smask1= (unsigned long long*)p; p += sz_smask1;
    unsigned long long* smask2= (unsigned long long*)p; p += sz_smask2;
    // total ~64 MB

    const double sc27 = 1.0 / 134217728.0;
    const double sc26 = 1.0 / 67108864.0;
    const int cshift = 3, CW = FW >> 3;      // 8 chunks x 32 words

    // --- prep ---
    spike2mask_kernel<<<dim3(5, FW, B), dim3(256), 0, stream>>>(x, cmask);
    quant_w1_kernel<<<dim3(F0 / 32, OP1 / 32), dim3(256), 0, stream>>>(W1, QT);
    quant_small_kernel<<<dim3((O1 * OP2 + 255) / 256), dim3(256), 0, stream>>>(
        W2, Q2T, O2, O1, OP2);
    quant_small_kernel<<<dim3((O2 * OP3 + 255) / 256), dim3(256), 0, stream>>>(
        W3, Q3T, O3, O2, OP3);

    // --- layer 1 ---
    sparse_gemm_kernel<<<dim3(NCOLS << cshift), dim3(128), 0, stream>>>(
        QT, cmask, zpart, OP1, FW, CW, cshift);
    redpsp_kernel<<<dim3(OP1 / 16, B), dim3(320), 0, stream>>>(
        zpart, u1, OP1, O1, 8, sc27);
    spike_kernel<<<dim3(W1M, B), dim3(64), 0, stream>>>(u1, smask1, (float*)0, O1, W1M);

    // --- layer 2 ---
    sparse_gemm_kernel<<<dim3(NCOLS), dim3(128), 0, stream>>>(
        Q2T, smask1, z2, OP2, W1M, W1M, 0);
    redpsp_kernel<<<dim3(OP2 / 16, B), dim3(320), 0, stream>>>(
        z2, u2, OP2, O2, 1, sc26);
    spike_kernel<<<dim3(W2M, B), dim3(64), 0, stream>>>(u2, smask2, (float*)0, O2, W2M);

    // --- layer 3 ---
    sparse_gemm_kernel<<<dim3(NCOLS), dim3(128), 0, stream>>>(
        Q3T, smask2, z3, OP3, W2M, W2M, 0);
    redpsp_kernel<<<dim3(OP3 / 16, B), dim3(320), 0, stream>>>(
        z3, u3, OP3, O3, 1, sc26);
    spike_kernel<<<dim3(1, B), dim3(64), 0, stream>>>(u3, (unsigned long long*)0, out, O3, 0);
}

// Round 9
// 478.266 us; speedup vs baseline: 10.6242x; 1.2203x over previous
//
#include <hip/hip_runtime.h>

// ---------------------------------------------------------------------------
// SLAYER SNN on MI355X — all-sparse exact-integer pipeline.
//   q[o,f] = rint(W[o,f]*2^s) (i32; s=27 for W1, s=26 for W2/W3).
//   z*2^s = sum over active f of q[o,f], i32 per chunk, chunk partials summed
//   in i64 -> EXACT, order-independent. Quant error ~1e-7 vs margins ~1e-5.
// Layer-1 gather XCD-chunked (8 chunks -> per-XCD-L2-resident QT slices).
// Round 9: latency-tail fixes (numerics bit-identical to round 8):
//  - spike: 256-thr dbuf staging (waves 1-3 stage c+1 || wave 0 LIF on c)
//  - redpsp: compile-time NCHUNK -> unrolled, pipelined chunk loads
//  - spike2mask: transposed LDS tile, conflict-free write AND ballot read
// ---------------------------------------------------------------------------

#define B   8
#define T   300
#define F0  16384
#define O1  410
#define OP1 416
#define O2  240
#define OP2 240
#define O3  10
#define OP3 16
#define FW  256          // 64-bit words per layer-1 column mask
#define W1M 7            // words per layer-1 output mask (410 -> 7)
#define W2M 4            // words per layer-2 output mask (240 -> 4)
#define NCOLS (B*T)      // 2400
#define LCAP 2048

__global__ __launch_bounds__(256) void spike2mask_kernel(
    const float* __restrict__ X, unsigned long long* __restrict__ cmask)
{
    __shared__ float tileT[64][65];    // [t-local][f-local], conflict-free
    int tt = blockIdx.x;
    int fb = blockIdx.y;
    int b  = blockIdx.z;
    int t0 = tt * 64, f0 = fb * 64;
    int tid = threadIdx.x;

    const float* Xb = X + ((size_t)b * F0 + f0) * T;
    int fl = tid >> 4;                 // 0..15
    int tq = (tid & 15) * 4;           // t-quad within tile
    #pragma unroll
    for (int i = 0; i < 4; ++i) {
        int fr = fl + i * 16;
        int t  = t0 + tq;
        float4 v = make_float4(0.f, 0.f, 0.f, 0.f);
        if (t < T) v = *(const float4*)(Xb + (size_t)fr * T + t);  // T%4==0
        tileT[tq + 0][fr] = v.x;
        tileT[tq + 1][fr] = v.y;
        tileT[tq + 2][fr] = v.z;
        tileT[tq + 3][fr] = v.w;
    }
    __syncthreads();

    int w = tid >> 6, l = tid & 63;
    #pragma unroll
    for (int j = 0; j < 16; ++j) {
        int c = w * 16 + j;                                  // t-local
        unsigned long long m = __ballot(tileT[c][l] != 0.0f);
        int t = t0 + c;
        if (l == 0 && t < T)
            cmask[(size_t)(b * T + t) * FW + fb] = m;
    }
}

__global__ __launch_bounds__(256) void quant_w1_kernel(
    const float* __restrict__ W, int* __restrict__ QT)
{
    __shared__ float tile[32][33];
    int f0 = blockIdx.x * 32;
    int o0 = blockIdx.y * 32;
    int tid = threadIdx.x;
    int c = tid & 31, r = tid >> 5;
    #pragma unroll
    for (int i = 0; i < 4; ++i) {
        int o = o0 + r + i * 8, f = f0 + c;
        tile[r + i * 8][c] = (o < O1) ? W[(size_t)o * F0 + f] : 0.0f;
    }
    __syncthreads();
    #pragma unroll
    for (int i = 0; i < 4; ++i) {
        int fr = r + i * 8;
        int o  = o0 + c;
        double w = (double)tile[c][fr] * 134217728.0;    // 2^27
        QT[(size_t)(f0 + fr) * OP1 + o] = (int)__double2ll_rn(w);
    }
}

__global__ __launch_bounds__(256) void quant_small_kernel(
    const float* __restrict__ W, int* __restrict__ QT, int O, int F, int OPAD)
{
    int idx = blockIdx.x * 256 + threadIdx.x;
    if (idx >= F * OPAD) return;
    int f = idx / OPAD, o = idx - f * OPAD;
    double v = (o < O) ? (double)W[(size_t)o * F + f] : 0.0;
    QT[idx] = (int)__double2ll_rn(v * 67108864.0);       // 2^26
}

// ---------------------------------------------------------------------------
// Z[chunk][col][o] (i32) = sum_{f in mask words [chunk*CW, chunk*CW+CW)} QT[f][o]
// ---------------------------------------------------------------------------
__global__ __launch_bounds__(128) void sparse_gemm_kernel(
    const int* __restrict__ QT, const unsigned long long* __restrict__ cmask,
    int* __restrict__ Z, int OPAD, int W, int CW, int cshift)
{
    __shared__ int lf[LCAP];
    __shared__ int wsum[2];

    int chunk = blockIdx.x & ((1 << cshift) - 1);
    int col   = blockIdx.x >> cshift;
    int tid   = threadIdx.x;

    int wbase = col * W + chunk * CW;
    unsigned long long w0 = (2 * tid     < CW) ? cmask[wbase + 2 * tid]     : 0ULL;
    unsigned long long w1 = (2 * tid + 1 < CW) ? cmask[wbase + 2 * tid + 1] : 0ULL;
    int my = __popcll(w0) + __popcll(w1);

    int scan = my;
    #pragma unroll
    for (int d = 1; d < 64; d <<= 1) {
        int v = __shfl_up(scan, d);
        if ((tid & 63) >= d) scan += v;
    }
    if ((tid & 63) == 63) wsum[tid >> 6] = scan;
    __syncthreads();
    int off = ((tid >= 64) ? wsum[0] : 0) + scan - my;
    int n = wsum[0] + wsum[1];

    int f0e = (chunk * CW + 2 * tid) * 64;
    unsigned long long m = w0;
    while (m) {
        int bit = __ffsll(m) - 1;
        if (off < LCAP) lf[off] = (f0e + bit) * OPAD;
        ++off; m &= m - 1;
    }
    m = w1; f0e += 64;
    while (m) {
        int bit = __ffsll(m) - 1;
        if (off < LCAP) lf[off] = (f0e + bit) * OPAD;
        ++off; m &= m - 1;
    }
    __syncthreads();
    if (n > LCAP) n = LCAP;

    if (tid * 4 < OPAD) {
        int o = tid * 4;
        const int* bq = QT + o;
        int a0 = 0, a1 = 0, a2 = 0, a3 = 0;
        int i = 0;
        for (; i + 8 <= n; i += 8) {
            int4 ia = *(const int4*)&lf[i];
            int4 ib = *(const int4*)&lf[i + 4];
            int e0 = __builtin_amdgcn_readfirstlane(ia.x);
            int e1 = __builtin_amdgcn_readfirstlane(ia.y);
            int e2 = __builtin_amdgcn_readfirstlane(ia.z);
            int e3 = __builtin_amdgcn_readfirstlane(ia.w);
            int e4 = __builtin_amdgcn_readfirstlane(ib.x);
            int e5 = __builtin_amdgcn_readfirstlane(ib.y);
            int e6 = __builtin_amdgcn_readfirstlane(ib.z);
            int e7 = __builtin_amdgcn_readfirstlane(ib.w);
            int4 q0 = *(const int4*)(bq + e0);
            int4 q1 = *(const int4*)(bq + e1);
            int4 q2 = *(const int4*)(bq + e2);
            int4 q3 = *(const int4*)(bq + e3);
            int4 q4 = *(const int4*)(bq + e4);
            int4 q5 = *(const int4*)(bq + e5);
            int4 q6 = *(const int4*)(bq + e6);
            int4 q7 = *(const int4*)(bq + e7);
            a0 += q0.x; a1 += q0.y; a2 += q0.z; a3 += q0.w;
            a0 += q1.x; a1 += q1.y; a2 += q1.z; a3 += q1.w;
            a0 += q2.x; a1 += q2.y; a2 += q2.z; a3 += q2.w;
            a0 += q3.x; a1 += q3.y; a2 += q3.z; a3 += q3.w;
            a0 += q4.x; a1 += q4.y; a2 += q4.z; a3 += q4.w;
            a0 += q5.x; a1 += q5.y; a2 += q5.z; a3 += q5.w;
            a0 += q6.x; a1 += q6.y; a2 += q6.z; a3 += q6.w;
            a0 += q7.x; a1 += q7.y; a2 += q7.z; a3 += q7.w;
        }
        for (; i < n; ++i) {
            int e = __builtin_amdgcn_readfirstlane(lf[i]);
            int4 q = *(const int4*)(bq + e);
            a0 += q.x; a1 += q.y; a2 += q.z; a3 += q.w;
        }
        int* zb = Z + ((size_t)chunk * NCOLS + col) * OPAD + o;
        *(int4*)zb = make_int4(a0, a1, a2, a3);
    }
}

// ---------------------------------------------------------------------------
// Fused chunk-reduce + psp conv; NCHUNK compile-time -> pipelined loads.
// ---------------------------------------------------------------------------
template<int NCHUNK>
__global__ __launch_bounds__(320) void redpsp_kernel(
    const int* __restrict__ Z, double* __restrict__ U,
    int OPAD, int O, double scale)
{
    __shared__ double zs[16][304];
    __shared__ double eps[100];
    int og = blockIdx.x, b = blockIdx.y;
    int o0 = og * 16;
    int tid = threadIdx.x;

    if (tid < 100) {
        double td = (double)tid;
        eps[tid] = (td / 10.0) * exp(1.0 - td / 10.0);
    }
    int ol = tid & 15, tg = tid >> 4;            // tg 0..19
    #pragma unroll 3
    for (int tt = 0; tt < 15; ++tt) {
        int t = tg + tt * 20;                    // < 300 always
        const int* zp = Z + ((size_t)(b * T + t)) * OPAD + o0 + ol;
        long long s = 0;
        #pragma unroll
        for (int c = 0; c < NCHUNK; ++c)
            s += zp[(size_t)c * NCOLS * OPAD];
        zs[ol][t] = (double)s * scale;
    }
    __syncthreads();

    if (tid < T) {
        double sum[16];
        #pragma unroll
        for (int o = 0; o < 16; ++o) sum[o] = 0.0;
        int kmax = tid < 99 ? tid : 99;
        for (int k = 0; k <= kmax; ++k) {
            double e = eps[k];
            #pragma unroll
            for (int o = 0; o < 16; ++o)
                sum[o] = fma(e, zs[o][tid - k], sum[o]);
        }
        #pragma unroll
        for (int o = 0; o < 16; ++o) {
            int oo = o0 + o;
            if (oo < O) U[((size_t)b * O + oo) * T + tid] = sum[o];
        }
    }
}

// ---------------------------------------------------------------------------
// Spike LIF, double-buffered: waves 1-3 stage chunk c+1 while wave 0 runs the
// sequential recurrence on chunk c. Same E/G update order as round 8
// (bit-identical spikes).
// ---------------------------------------------------------------------------
#define SPIKE_STAGE(BUF, T0, TIDX, NT)                                        \
    { int cl_ = T - (T0); if (cl_ > 64) cl_ = 64;                             \
      for (int idx = (TIDX); idx < 64 * 64; idx += (NT)) {                    \
        int r_ = idx >> 6, tl_ = idx & 63;                                    \
        int orow_ = w * 64 + r_; if (orow_ >= O) orow_ = O - 1;               \
        if (tl_ < cl_)                                                        \
            us[BUF][r_][tl_] = U[((size_t)b * O + orow_) * T + (T0) + tl_]; } }

__global__ __launch_bounds__(256) void spike_kernel(
    const double* __restrict__ U, unsigned long long* __restrict__ smask,
    float* __restrict__ sout, int O, int words)
{
    __shared__ double us[2][64][65];
    int w = blockIdx.x, b = blockIdx.y;
    int tid = threadIdx.x;
    int lane = tid & 63;
    int o = w * 64 + lane;
    bool active = (o < O);

    const double alpha = exp(-0.5);
    const double A31   = exp(-15.5);
    const double c0    = -10.0 * exp(1.0);

    SPIKE_STAGE(0, 0, tid, 256);
    __syncthreads();

    double E = 0.0, G = 0.0;
    unsigned hist = 0u;                       // bit k = spike at lag k+1
    float* so = (sout && active) ? sout + ((size_t)b * O + o) * T : (float*)0;

    const int NCH = (T + 63) / 64;            // 5
    for (int c = 0; c < NCH; ++c) {
        int cur = c & 1;
        if (tid >= 64) {
            if (c + 1 < NCH) SPIKE_STAGE(cur ^ 1, (c + 1) * 64, tid - 64, 192);
        } else {
            int t0 = c * 64;
            int cl = T - t0; if (cl > 64) cl = 64;
            for (int tl = 0; tl < cl; ++tl) {
                double uval = active ? us[cur][lane][tl] : -1.0e300;
                double v = uval + c0 * G;
                bool sp = (v >= 10.0);
                unsigned long long bal = __ballot(sp);
                if (smask && lane == 0)
                    smask[((size_t)b * T + t0 + tl) * words + w] = bal;
                if (so) so[t0 + tl] = sp ? 1.0f : 0.0f;

                double sN  = sp ? 1.0 : 0.0;
                double s31 = ((hist >> 30) & 1u) ? 1.0 : 0.0;
                double Em  = E - A31 * s31;
                double Gm  = G - 31.0 * A31 * s31;
                G = alpha * (sN + Gm + Em);
                E = alpha * (sN + Em);
                hist = (hist << 1) | (sp ? 1u : 0u);
            }
        }
        __syncthreads();
    }
}

// ---------------------------------------------------------------------------
extern "C" void kernel_launch(void* const* d_in, const int* in_sizes, int n_in,
                              void* d_out, int out_size, void* d_ws, size_t ws_size,
                              hipStream_t stream)
{
    const float* x  = (const float*)d_in[0];
    const float* W1 = (const float*)d_in[1];
    const float* W2 = (const float*)d_in[2];
    const float* W3 = (const float*)d_in[3];
    float* out = (float*)d_out;

    const size_t N1 = (size_t)B * O1 * T;
    const size_t N2 = (size_t)B * O2 * T;
    const size_t N3 = (size_t)B * O3 * T;

    const size_t sz_QT     = (size_t)F0 * OP1 * 4;          // 27.3 MB
    const size_t sz_zpart  = (size_t)8 * NCOLS * OP1 * 4;   // 16.0 MB
    const size_t sz_u1     = N1 * 8;
    const size_t sz_z2     = (size_t)NCOLS * OP2 * 4;
    const size_t sz_u2     = N2 * 8;
    const size_t sz_z3     = (size_t)NCOLS * OP3 * 4;
    const size_t sz_u3     = N3 * 8;
    const size_t sz_cmask  = (size_t)NCOLS * FW * 8;
    const size_t sz_Q2T    = (size_t)O1 * OP2 * 4;
    const size_t sz_Q3T    = (size_t)O2 * OP3 * 4;
    const size_t sz_smask1 = (size_t)NCOLS * W1M * 8;
    const size_t sz_smask2 = (size_t)NCOLS * W2M * 8;

    char* p = (char*)d_ws;
    int*                QT    = (int*)p;                p += sz_QT;
    int*                zpart = (int*)p;                p += sz_zpart;
    double*             u1    = (double*)p;             p += sz_u1;
    int*                z2    = (int*)p;                p += sz_z2;
    double*             u2    = (double*)p;             p += sz_u2;
    int*                z3    = (int*)p;                p += sz_z3;
    double*             u3    = (double*)p;             p += sz_u3;
    unsigned long long* cmask = (unsigned long long*)p; p += sz_cmask;
    int*                Q2T   = (int*)p;                p += sz_Q2T;
    int*                Q3T   = (int*)p;                p += sz_Q3T;
    unsigned long long* smask1= (unsigned long long*)p; p += sz_smask1;
    unsigned long long* smask2= (unsigned long long*)p; p += sz_smask2;

    const double sc27 = 1.0 / 134217728.0;
    const double sc26 = 1.0 / 67108864.0;
    const int cshift = 3, CW = FW >> 3;      // 8 chunks x 32 words

    // --- prep ---
    spike2mask_kernel<<<dim3(5, FW, B), dim3(256), 0, stream>>>(x, cmask);
    quant_w1_kernel<<<dim3(F0 / 32, OP1 / 32), dim3(256), 0, stream>>>(W1, QT);
    quant_small_kernel<<<dim3((O1 * OP2 + 255) / 256), dim3(256), 0, stream>>>(
        W2, Q2T, O2, O1, OP2);
    quant_small_kernel<<<dim3((O2 * OP3 + 255) / 256), dim3(256), 0, stream>>>(
        W3, Q3T, O3, O2, OP3);

    // --- layer 1 ---
    sparse_gemm_kernel<<<dim3(NCOLS << cshift), dim3(128), 0, stream>>>(
        QT, cmask, zpart, OP1, FW, CW, cshift);
    redpsp_kernel<8><<<dim3(OP1 / 16, B), dim3(320), 0, stream>>>(
        zpart, u1, OP1, O1, sc27);
    spike_kernel<<<dim3(W1M, B), dim3(256), 0, stream>>>(u1, smask1, (float*)0, O1, W1M);

    // --- layer 2 ---
    sparse_gemm_kernel<<<dim3(NCOLS), dim3(128), 0, stream>>>(
        Q2T, smask1, z2, OP2, W1M, W1M, 0);
    redpsp_kernel<1><<<dim3(OP2 / 16, B), dim3(320), 0, stream>>>(
        z2, u2, OP2, O2, sc26);
    spike_kernel<<<dim3(W2M, B), dim3(256), 0, stream>>>(u2, smask2, (float*)0, O2, W2M);

    // --- layer 3 ---
    sparse_gemm_kernel<<<dim3(NCOLS), dim3(128), 0, stream>>>(
        Q3T, smask2, z3, OP3, W2M, W2M, 0);
    redpsp_kernel<1><<<dim3(OP3 / 16, B), dim3(320), 0, stream>>>(
        z3, u3, OP3, O3, sc26);
    spike_kernel<<<dim3(1, B), dim3(256), 0, stream>>>(u3, (unsigned long long*)0, out, O3, 0);
}

// Round 10
// 372.564 us; speedup vs baseline: 13.6384x; 1.2837x over previous
//
#include <hip/hip_runtime.h>

// ---------------------------------------------------------------------------
// SLAYER SNN on MI355X — layer 1 on i8 MATRIX CORES, exact integer limbs.
//   q[o,f] = rint(W1[o,f]*2^27) (i32)  ==  l0 + 256 l1 + 65536 l2 + 2^24 l3
//   (signed-digit i8 limbs, exact). z*2^27 = sum_l 2^(8l) * (limb_l GEMM x),
//   x in {0,1} as i8, accumulated by v_mfma_i32_32x32x32_i8 (i32, exact,
//   |sums| <= ~1e6 << 2^31). z is BIT-IDENTICAL to the proven sparse path.
// Operands are pre-swizzled in GLOBAL memory to the exact MFMA fragment
// order (16 B per lane, contiguous per wave) -> the GEMM kernel has NO LDS
// and NO barriers; it streams A/B from L2 and accumulates in registers.
//   A frag (32x32): lane l holds row=l&31, k=(l>>5)*16+i  -> word ks*64+l
//   B frag:         lane l holds col=l&31, k=(l>>5)*16+i  -> word ks*64+l
//   C/D:            col=lane&31, row=(r&3)+8*(r>>2)+4*(lane>>5)
// Layers 2/3 keep the sparse-integer path (smask from spike ballots).
// Spike LIF: exact finite-window recurrence (E,G + lag-31 evict), dbuf LDS.
// ---------------------------------------------------------------------------

#define B   8
#define T   300
#define F0  16384
#define O1  410
#define O2  240
#define OP2 240
#define O3  10
#define OP3 16
#define W1M 7            // words per layer-1 output mask (410 -> 7)
#define W2M 4            // words per layer-2 output mask (240 -> 4)
#define NCOLS (B*T)      // 2400
#define LCAP 2048
#define MTOT 1664        // 4 limb planes x 416 padded rows
#define PPLANE (MTOT*NCOLS)   // i32 elements per kc plane

typedef int  int32x4  __attribute__((ext_vector_type(4)));
typedef int  int32x16 __attribute__((ext_vector_type(16)));

// ---------------------------------------------------------------------------
// Bswz builder: x[b][f][t] f32 -> swizzled i8 B operand.
// Bswz chunk for (b, kit=f/64): 10 n-groups (32 t-cols) x 2048 B.
//   byte addr = ((b*256+kit)*10 + t/32)*2048 + (ks*64 + (t&31) + 32*hb)*16 + i
//   where k_local = f&63 = ks*32 + hb*16 + i.
// ---------------------------------------------------------------------------
__global__ __launch_bounds__(256) void transpose_x_kernel(
    const float* __restrict__ X, char* __restrict__ Bswz)
{
    __shared__ float tileT[64][65];    // [t-local][f-local]
    int tt = blockIdx.x;               // t-tile (0..4)
    int kit = blockIdx.y;              // f-word (0..255)
    int b  = blockIdx.z;
    int t0 = tt * 64, f0 = kit * 64;
    int tid = threadIdx.x;

    const float* Xb = X + ((size_t)b * F0 + f0) * T;
    int fl = tid >> 4;                 // 0..15
    int tq = (tid & 15) * 4;           // t-quad
    #pragma unroll
    for (int i = 0; i < 4; ++i) {
        int fr = fl + i * 16;
        int t  = t0 + tq;
        float4 v = make_float4(0.f, 0.f, 0.f, 0.f);
        if (t < T) v = *(const float4*)(Xb + (size_t)fr * T + t);
        tileT[tq + 0][fr] = v.x;
        tileT[tq + 1][fr] = v.y;
        tileT[tq + 2][fr] = v.z;
        tileT[tq + 3][fr] = v.w;
    }
    __syncthreads();

    int tl = tid & 63;                 // t within tile
    int fg = tid >> 6;                 // 16-f group (0..3)
    unsigned d[4] = {0u, 0u, 0u, 0u};
    #pragma unroll
    for (int j = 0; j < 16; ++j) {
        unsigned bit = (tileT[tl][fg * 16 + j] != 0.0f) ? 1u : 0u;
        d[j >> 2] |= bit << (8 * (j & 3));
    }
    int ng   = (t0 + tl) >> 5;                         // global t / 32
    int word = (fg >> 1) * 64 + (tl & 31) + 32 * (fg & 1);
    size_t addr = ((size_t)(b * 256 + kit) * 10 + ng) * 2048 + (size_t)word * 16;
    *(int32x4*)(Bswz + addr) = (int32x4){(int)d[0], (int)d[1], (int)d[2], (int)d[3]};
}

// ---------------------------------------------------------------------------
// Aswz builder: W1 -> 4 signed i8 limb planes, swizzled.
//   m = l*416 + o (0..1663); mt=m>>7, r=m&127, g=r>>5, row=r&31
//   byte addr = ((mt*256+kit)*4 + g)*2048 + (ks*64 + row + 32*hb)*16 + (f&15)
// ---------------------------------------------------------------------------
__global__ __launch_bounds__(256) void quant_limb_kernel(
    const float* __restrict__ W, char* __restrict__ Aswz)
{
    int o  = blockIdx.y;               // 0..415
    int f0 = blockIdx.x * 1024;
    int f  = f0 + threadIdx.x * 4;

    float4 w4 = make_float4(0.f, 0.f, 0.f, 0.f);
    if (o < O1) w4 = *(const float4*)(W + (size_t)o * F0 + f);

    int lb[4][4];
    float wv[4] = {w4.x, w4.y, w4.z, w4.w};
    #pragma unroll
    for (int e = 0; e < 4; ++e) {
        int q = (int)__double2ll_rn((double)wv[e] * 134217728.0);   // 2^27
        int l0 = (int)(signed char)(q & 255);  q = (q - l0) >> 8;
        int l1 = (int)(signed char)(q & 255);  q = (q - l1) >> 8;
        int l2 = (int)(signed char)(q & 255);  int l3 = (q - l2) >> 8;
        lb[0][e] = l0; lb[1][e] = l1; lb[2][e] = l2; lb[3][e] = l3;
    }

    int kit = f >> 6, kq = f & 63;
    int ks = kq >> 5, hb = (kq >> 4) & 1, i = kq & 15;
    #pragma unroll
    for (int l = 0; l < 4; ++l) {
        unsigned d = (unsigned)(lb[l][0] & 255) | ((unsigned)(lb[l][1] & 255) << 8) |
                     ((unsigned)(lb[l][2] & 255) << 16) | ((unsigned)(lb[l][3] & 255) << 24);
        int m = l * 416 + o;
        int mt = m >> 7, r = m & 127, g = r >> 5, row = r & 31;
        int word = ks * 64 + row + 32 * hb;
        size_t addr = ((size_t)(mt * 256 + kit) * 4 + g) * 2048 + (size_t)word * 16 + i;
        *(unsigned*)(Aswz + addr) = d;
    }
}

__global__ __launch_bounds__(256) void quant_small_kernel(
    const float* __restrict__ W, int* __restrict__ QT, int O, int F, int OPAD)
{
    int idx = blockIdx.x * 256 + threadIdx.x;
    if (idx >= F * OPAD) return;
    int f = idx / OPAD, o = idx - f * OPAD;
    double v = (o < O) ? (double)W[(size_t)o * F + f] : 0.0;
    QT[idx] = (int)__double2ll_rn(v * 67108864.0);       // 2^26
}

// ---------------------------------------------------------------------------
// LDS-free, barrier-free i8 MFMA GEMM: P[kc][m][col] = limbs x spikes.
// Grid (bh=16, mt=13, kc=2); block 256 = 4 waves (2m x 2n).
// ---------------------------------------------------------------------------
__global__ __launch_bounds__(256) void mfma_gemm_kernel(
    const char* __restrict__ Aswz, const char* __restrict__ Bswz,
    int* __restrict__ P)
{
    int bh = blockIdx.x;               // b*2 + half
    int mt = blockIdx.y;               // 0..12
    int kc = blockIdx.z;               // 0..1
    int b = bh >> 1, half = bh & 1;

    int tid = threadIdx.x;
    int lane = tid & 63, wv = tid >> 6;
    int wm = wv >> 1, wn = wv & 1;
    int ng0 = wn * 3;
    int nfr = wn ? 2 : 3;              // wave-uniform

    const char* Ab = Aswz + ((size_t)(mt * 256 + kc * 128) * 4 + wm * 2) * 2048
                          + (size_t)lane * 16;
    const char* Bb = Bswz + ((size_t)(b * 256 + kc * 128) * 10 + half * 5 + ng0) * 2048
                          + (size_t)lane * 16;

    int32x16 acc[2][3];
    #pragma unroll
    for (int fm = 0; fm < 2; ++fm)
        #pragma unroll
        for (int fn = 0; fn < 3; ++fn)
            acc[fm][fn] = (int32x16){0,0,0,0,0,0,0,0,0,0,0,0,0,0,0,0};

    for (int it = 0; it < 128; ++it) {
        int32x4 a[2][2], bv[3][2];
        #pragma unroll
        for (int fm = 0; fm < 2; ++fm)
            #pragma unroll
            for (int ks = 0; ks < 2; ++ks)
                a[fm][ks] = *(const int32x4*)(Ab + fm * 2048 + ks * 1024);
        #pragma unroll
        for (int fn = 0; fn < 3; ++fn)
            if (fn < nfr)
                #pragma unroll
                for (int ks = 0; ks < 2; ++ks)
                    bv[fn][ks] = *(const int32x4*)(Bb + fn * 2048 + ks * 1024);

        #pragma unroll
        for (int ks = 0; ks < 2; ++ks)
            #pragma unroll
            for (int fm = 0; fm < 2; ++fm)
                #pragma unroll
                for (int fn = 0; fn < 3; ++fn)
                    if (fn < nfr)
                        acc[fm][fn] = __builtin_amdgcn_mfma_i32_32x32x32_i8(
                            a[fm][ks], bv[fn][ks], acc[fm][fn], 0, 0, 0);

        Ab += 8192;        // 4 g-groups * 2048
        Bb += 20480;       // 10 n-groups * 2048
    }

    int* Pk = P + (size_t)kc * PPLANE;
    #pragma unroll
    for (int fm = 0; fm < 2; ++fm) {
        #pragma unroll
        for (int fn = 0; fn < 3; ++fn) {
            if (fn >= nfr) continue;
            int t = (half * 5 + ng0 + fn) * 32 + (lane & 31);   // global t
            if (t >= T) continue;
            #pragma unroll
            for (int r = 0; r < 16; ++r) {
                int m = mt * 128 + wm * 64 + fm * 32
                      + (r & 3) + 8 * (r >> 2) + 4 * (lane >> 5);
                Pk[(size_t)m * NCOLS + b * T + t] = acc[fm][fn][r];
            }
        }
    }
}

// ---------------------------------------------------------------------------
// Combine limb planes (exact i64) + psp conv for layer 1.
//   s(o,col) = sum_kc [ p0 + (p1<<8) + (p2<<16) + (p3<<24) ];  z = s * 2^-27
// ---------------------------------------------------------------------------
__global__ __launch_bounds__(320) void redpsp_mfma_kernel(
    const int* __restrict__ P, double* __restrict__ U)
{
    __shared__ double zs[16][304];
    __shared__ double eps[100];
    int og = blockIdx.x, b = blockIdx.y;
    int o0 = og * 16;
    int tid = threadIdx.x;
    const double sc27 = 1.0 / 134217728.0;

    if (tid < 100) {
        double td = (double)tid;
        eps[tid] = (td / 10.0) * exp(1.0 - td / 10.0);
    }
    if (tid < T) {
        int col = b * T + tid;
        #pragma unroll 2
        for (int ol = 0; ol < 16; ++ol) {
            int o = o0 + ol;
            long long s = 0;
            #pragma unroll
            for (int kc = 0; kc < 2; ++kc) {
                const int* pp = P + (size_t)kc * PPLANE + col;
                long long p0 = pp[(size_t)(0 * 416 + o) * NCOLS];
                long long p1 = pp[(size_t)(1 * 416 + o) * NCOLS];
                long long p2 = pp[(size_t)(2 * 416 + o) * NCOLS];
                long long p3 = pp[(size_t)(3 * 416 + o) * NCOLS];
                s += p0 + (p1 << 8) + (p2 << 16) + (p3 << 24);
            }
            zs[ol][tid] = (double)s * sc27;
        }
    }
    __syncthreads();

    if (tid < T) {
        double sum[16];
        #pragma unroll
        for (int o = 0; o < 16; ++o) sum[o] = 0.0;
        int kmax = tid < 99 ? tid : 99;
        for (int k = 0; k <= kmax; ++k) {
            double e = eps[k];
            #pragma unroll
            for (int o = 0; o < 16; ++o)
                sum[o] = fma(e, zs[o][tid - k], sum[o]);
        }
        #pragma unroll
        for (int o = 0; o < 16; ++o) {
            int oo = o0 + o;
            if (oo < O1) U[((size_t)b * O1 + oo) * T + tid] = sum[o];
        }
    }
}

// ---------------------------------------------------------------------------
// Sparse integer GEMM for layers 2/3 (unchanged, proven).
// ---------------------------------------------------------------------------
__global__ __launch_bounds__(128) void sparse_gemm_kernel(
    const int* __restrict__ QT, const unsigned long long* __restrict__ cmask,
    int* __restrict__ Z, int OPAD, int W, int CW, int cshift)
{
    __shared__ int lf[LCAP];
    __shared__ int wsum[2];

    int chunk = blockIdx.x & ((1 << cshift) - 1);
    int col   = blockIdx.x >> cshift;
    int tid   = threadIdx.x;

    int wbase = col * W + chunk * CW;
    unsigned long long w0 = (2 * tid     < CW) ? cmask[wbase + 2 * tid]     : 0ULL;
    unsigned long long w1 = (2 * tid + 1 < CW) ? cmask[wbase + 2 * tid + 1] : 0ULL;
    int my = __popcll(w0) + __popcll(w1);

    int scan = my;
    #pragma unroll
    for (int d = 1; d < 64; d <<= 1) {
        int v = __shfl_up(scan, d);
        if ((tid & 63) >= d) scan += v;
    }
    if ((tid & 63) == 63) wsum[tid >> 6] = scan;
    __syncthreads();
    int off = ((tid >= 64) ? wsum[0] : 0) + scan - my;
    int n = wsum[0] + wsum[1];

    int f0e = (chunk * CW + 2 * tid) * 64;
    unsigned long long m = w0;
    while (m) {
        int bit = __ffsll(m) - 1;
        if (off < LCAP) lf[off] = (f0e + bit) * OPAD;
        ++off; m &= m - 1;
    }
    m = w1; f0e += 64;
    while (m) {
        int bit = __ffsll(m) - 1;
        if (off < LCAP) lf[off] = (f0e + bit) * OPAD;
        ++off; m &= m - 1;
    }
    __syncthreads();
    if (n > LCAP) n = LCAP;

    if (tid * 4 < OPAD) {
        int o = tid * 4;
        const int* bq = QT + o;
        int a0 = 0, a1 = 0, a2 = 0, a3 = 0;
        int i = 0;
        for (; i + 8 <= n; i += 8) {
            int4 ia = *(const int4*)&lf[i];
            int4 ib = *(const int4*)&lf[i + 4];
            int e0 = __builtin_amdgcn_readfirstlane(ia.x);
            int e1 = __builtin_amdgcn_readfirstlane(ia.y);
            int e2 = __builtin_amdgcn_readfirstlane(ia.z);
            int e3 = __builtin_amdgcn_readfirstlane(ia.w);
            int e4 = __builtin_amdgcn_readfirstlane(ib.x);
            int e5 = __builtin_amdgcn_readfirstlane(ib.y);
            int e6 = __builtin_amdgcn_readfirstlane(ib.z);
            int e7 = __builtin_amdgcn_readfirstlane(ib.w);
            int4 q0 = *(const int4*)(bq + e0);
            int4 q1 = *(const int4*)(bq + e1);
            int4 q2 = *(const int4*)(bq + e2);
            int4 q3 = *(const int4*)(bq + e3);
            int4 q4 = *(const int4*)(bq + e4);
            int4 q5 = *(const int4*)(bq + e5);
            int4 q6 = *(const int4*)(bq + e6);
            int4 q7 = *(const int4*)(bq + e7);
            a0 += q0.x; a1 += q0.y; a2 += q0.z; a3 += q0.w;
            a0 += q1.x; a1 += q1.y; a2 += q1.z; a3 += q1.w;
            a0 += q2.x; a1 += q2.y; a2 += q2.z; a3 += q2.w;
            a0 += q3.x; a1 += q3.y; a2 += q3.z; a3 += q3.w;
            a0 += q4.x; a1 += q4.y; a2 += q4.z; a3 += q4.w;
            a0 += q5.x; a1 += q5.y; a2 += q5.z; a3 += q5.w;
            a0 += q6.x; a1 += q6.y; a2 += q6.z; a3 += q6.w;
            a0 += q7.x; a1 += q7.y; a2 += q7.z; a3 += q7.w;
        }
        for (; i < n; ++i) {
            int e = __builtin_amdgcn_readfirstlane(lf[i]);
            int4 q = *(const int4*)(bq + e);
            a0 += q.x; a1 += q.y; a2 += q.z; a3 += q.w;
        }
        int* zb = Z + ((size_t)chunk * NCOLS + col) * OPAD + o;
        *(int4*)zb = make_int4(a0, a1, a2, a3);
    }
}

// ---------------------------------------------------------------------------
// Sparse-path reduce + psp conv (layers 2/3).
// ---------------------------------------------------------------------------
template<int NCHUNK>
__global__ __launch_bounds__(320) void redpsp_kernel(
    const int* __restrict__ Z, double* __restrict__ U,
    int OPAD, int O, double scale)
{
    __shared__ double zs[16][304];
    __shared__ double eps[100];
    int og = blockIdx.x, b = blockIdx.y;
    int o0 = og * 16;
    int tid = threadIdx.x;

    if (tid < 100) {
        double td = (double)tid;
        eps[tid] = (td / 10.0) * exp(1.0 - td / 10.0);
    }
    int ol = tid & 15, tg = tid >> 4;
    #pragma unroll 3
    for (int tt = 0; tt < 15; ++tt) {
        int t = tg + tt * 20;
        const int* zp = Z + ((size_t)(b * T + t)) * OPAD + o0 + ol;
        long long s = 0;
        #pragma unroll
        for (int c = 0; c < NCHUNK; ++c)
            s += zp[(size_t)c * NCOLS * OPAD];
        zs[ol][t] = (double)s * scale;
    }
    __syncthreads();

    if (tid < T) {
        double sum[16];
        #pragma unroll
        for (int o = 0; o < 16; ++o) sum[o] = 0.0;
        int kmax = tid < 99 ? tid : 99;
        for (int k = 0; k <= kmax; ++k) {
            double e = eps[k];
            #pragma unroll
            for (int o = 0; o < 16; ++o)
                sum[o] = fma(e, zs[o][tid - k], sum[o]);
        }
        #pragma unroll
        for (int o = 0; o < 16; ++o) {
            int oo = o0 + o;
            if (oo < O) U[((size_t)b * O + oo) * T + tid] = sum[o];
        }
    }
}

// ---------------------------------------------------------------------------
// Spike LIF via exact finite-window recurrence, dbuf-staged (round 9 proven).
// ---------------------------------------------------------------------------
#define SPIKE_STAGE(BUF, T0, TIDX, NT)                                        \
    { int cl_ = T - (T0); if (cl_ > 64) cl_ = 64;                             \
      for (int idx = (TIDX); idx < 64 * 64; idx += (NT)) {                    \
        int r_ = idx >> 6, tl_ = idx & 63;                                    \
        int orow_ = w * 64 + r_; if (orow_ >= O) orow_ = O - 1;               \
        if (tl_ < cl_)                                                        \
            us[BUF][r_][tl_] = U[((size_t)b * O + orow_) * T + (T0) + tl_]; } }

__global__ __launch_bounds__(256) void spike_kernel(
    const double* __restrict__ U, unsigned long long* __restrict__ smask,
    float* __restrict__ sout, int O, int words)
{
    __shared__ double us[2][64][65];
    int w = blockIdx.x, b = blockIdx.y;
    int tid = threadIdx.x;
    int lane = tid & 63;
    int o = w * 64 + lane;
    bool active = (o < O);

    const double alpha = exp(-0.5);
    const double A31   = exp(-15.5);
    const double c0    = -10.0 * exp(1.0);

    SPIKE_STAGE(0, 0, tid, 256);
    __syncthreads();

    double E = 0.0, G = 0.0;
    unsigned hist = 0u;
    float* so = (sout && active) ? sout + ((size_t)b * O + o) * T : (float*)0;

    const int NCH = (T + 63) / 64;
    for (int c = 0; c < NCH; ++c) {
        int cur = c & 1;
        if (tid >= 64) {
            if (c + 1 < NCH) SPIKE_STAGE(cur ^ 1, (c + 1) * 64, tid - 64, 192);
        } else {
            int t0 = c * 64;
            int cl = T - t0; if (cl > 64) cl = 64;
            for (int tl = 0; tl < cl; ++tl) {
                double uval = active ? us[cur][lane][tl] : -1.0e300;
                double v = uval + c0 * G;
                bool sp = (v >= 10.0);
                unsigned long long bal = __ballot(sp);
                if (smask && lane == 0)
                    smask[((size_t)b * T + t0 + tl) * words + w] = bal;
                if (so) so[t0 + tl] = sp ? 1.0f : 0.0f;

                double sN  = sp ? 1.0 : 0.0;
                double s31 = ((hist >> 30) & 1u) ? 1.0 : 0.0;
                double Em  = E - A31 * s31;
                double Gm  = G - 31.0 * A31 * s31;
                G = alpha * (sN + Gm + Em);
                E = alpha * (sN + Em);
                hist = (hist << 1) | (sp ? 1u : 0u);
            }
        }
        __syncthreads();
    }
}

// ---------------------------------------------------------------------------
extern "C" void kernel_launch(void* const* d_in, const int* in_sizes, int n_in,
                              void* d_out, int out_size, void* d_ws, size_t ws_size,
                              hipStream_t stream)
{
    const float* x  = (const float*)d_in[0];
    const float* W1 = (const float*)d_in[1];
    const float* W2 = (const float*)d_in[2];
    const float* W3 = (const float*)d_in[3];
    float* out = (float*)d_out;

    const size_t sz_Aswz = (size_t)13 * 256 * 4 * 2048;      // 27.26 MB
    const size_t sz_Bswz = (size_t)8 * 256 * 10 * 2048;      // 41.94 MB
    const size_t sz_P    = (size_t)2 * PPLANE * 4;           // 31.95 MB
    const size_t sz_u1   = (size_t)B * O1 * T * 8;           //  7.87 MB
    const size_t sz_Q2T  = (size_t)O1 * OP2 * 4;
    const size_t sz_Q3T  = (size_t)O2 * OP3 * 4;

    char* p = (char*)d_ws;
    char*   Aswz = p;                   p += sz_Aswz;
    char*   Bswz = p;                   p += sz_Bswz;
    int*    P    = (int*)p;   char* pa = p;  p += sz_P;
    double* u1   = (double*)p;          p += sz_u1;
    int*    Q2T  = (int*)p;             p += sz_Q2T;
    int*    Q3T  = (int*)p;             p += sz_Q3T;
    // Aliased into P's region (P is dead after redpsp_mfma):
    int*                z2     = (int*)pa;                pa += (size_t)NCOLS * OP2 * 4;
    double*             u2     = (double*)pa;             pa += (size_t)B * O2 * T * 8;
    int*                z3     = (int*)pa;                pa += (size_t)NCOLS * OP3 * 4;
    double*             u3     = (double*)pa;             pa += (size_t)B * O3 * T * 8;
    unsigned long long* smask1 = (unsigned long long*)pa; pa += (size_t)NCOLS * W1M * 8;
    unsigned long long* smask2 = (unsigned long long*)pa; pa += (size_t)NCOLS * W2M * 8;

    const double sc26 = 1.0 / 67108864.0;

    // --- prep (independent) ---
    transpose_x_kernel<<<dim3(5, 256, B), dim3(256), 0, stream>>>(x, Bswz);
    quant_limb_kernel<<<dim3(16, 416), dim3(256), 0, stream>>>(W1, Aswz);
    quant_small_kernel<<<dim3((O1 * OP2 + 255) / 256), dim3(256), 0, stream>>>(
        W2, Q2T, O2, O1, OP2);
    quant_small_kernel<<<dim3((O2 * OP3 + 255) / 256), dim3(256), 0, stream>>>(
        W3, Q3T, O3, O2, OP3);

    // --- layer 1 (MFMA) ---
    mfma_gemm_kernel<<<dim3(16, 13, 2), dim3(256), 0, stream>>>(Aswz, Bswz, P);
    redpsp_mfma_kernel<<<dim3(26, B), dim3(320), 0, stream>>>(P, u1);
    spike_kernel<<<dim3(W1M, B), dim3(256), 0, stream>>>(u1, smask1, (float*)0, O1, W1M);

    // --- layer 2 (sparse) ---
    sparse_gemm_kernel<<<dim3(NCOLS), dim3(128), 0, stream>>>(
        Q2T, smask1, z2, OP2, W1M, W1M, 0);
    redpsp_kernel<1><<<dim3(OP2 / 16, B), dim3(320), 0, stream>>>(
        z2, u2, OP2, O2, sc26);
    spike_kernel<<<dim3(W2M, B), dim3(256), 0, stream>>>(u2, smask2, (float*)0, O2, W2M);

    // --- layer 3 (sparse) ---
    sparse_gemm_kernel<<<dim3(NCOLS), dim3(128), 0, stream>>>(
        Q3T, smask2, z3, OP3, W2M, W2M, 0);
    redpsp_kernel<1><<<dim3(OP3 / 16, B), dim3(320), 0, stream>>>(
        z3, u3, OP3, O3, sc26);
    spike_kernel<<<dim3(1, B), dim3(256), 0, stream>>>(u3, (unsigned long long*)0, out, O3, 0);
}